// Round 2
// baseline (2516.112 us; speedup 1.0000x reference)
//
#include <hip/hip_runtime.h>
#include <math.h>

#define N_NODES 100000
#define N_EDGES 3200000
#define F_IN 256
#define M_OUT 512            // 2*F_OUT concat
#define K_TOT 1024           // [x | Ax | A^2x | A^4x]
#define EPS_BN 1e-3f
#define NUM_CHUNKS 391       // ceil(100000/256) == number of row buckets
#define NB NUM_CHUNKS
#define EPB 16384            // edges per block in scatter pass 1

typedef __attribute__((ext_vector_type(8))) short short8;
typedef __attribute__((ext_vector_type(8))) ushort ushortx8;
typedef __attribute__((ext_vector_type(4))) float floatx4;

__device__ __forceinline__ ushort f2b(float f) {
    union { float f; unsigned u; } c; c.f = f;
    unsigned u = c.u;
    unsigned r = (u + 0x7FFFu + ((u >> 16) & 1u)) >> 16;   // RNE
    return (ushort)r;
}
__device__ __forceinline__ float b2f(ushort b) {
    union { unsigned u; float f; } c; c.u = ((unsigned)b) << 16;
    return c.f;
}

// ---------------- small utility kernels ----------------

__global__ void zero_i32(int* __restrict__ p, int n) {
    int i = blockIdx.x * blockDim.x + threadIdx.x;
    if (i < n) p[i] = 0;
}

__global__ void hist_kernel(const int* __restrict__ row, int* __restrict__ counts, int n) {
    int i = blockIdx.x * blockDim.x + threadIdx.x;
    if (i < n) atomicAdd(&counts[row[i]], 1);
}

__global__ void scan_chunk_sums(const int* __restrict__ counts, int* __restrict__ chunkSums, int n) {
    __shared__ int sm[256];
    int c = blockIdx.x;
    int t = threadIdx.x;
    int i = c * 256 + t;
    sm[t] = (i < n) ? counts[i] : 0;
    __syncthreads();
    for (int s = 128; s > 0; s >>= 1) {
        if (t < s) sm[t] += sm[t + s];
        __syncthreads();
    }
    if (t == 0) chunkSums[c] = sm[0];
}

__global__ void scan_spine(int* __restrict__ chunkSums, int numChunks, int* __restrict__ row_off, int n) {
    __shared__ int sm[512];
    int t = threadIdx.x;
    int v = (t < numChunks) ? chunkSums[t] : 0;
    sm[t] = v;
    __syncthreads();
    for (int s = 1; s < 512; s <<= 1) {
        int add = (t >= s) ? sm[t - s] : 0;
        __syncthreads();
        sm[t] += add;
        __syncthreads();
    }
    if (t < numChunks) chunkSums[t] = sm[t] - v;   // exclusive: bucket start offsets
    if (t == 511) row_off[n] = sm[511];
}

__global__ void scan_final(const int* __restrict__ counts, const int* __restrict__ chunkSums,
                           int* __restrict__ row_off, int n) {
    __shared__ int sm[256];
    int c = blockIdx.x;
    int t = threadIdx.x;
    int i = c * 256 + t;
    int v = (i < n) ? counts[i] : 0;
    sm[t] = v;
    __syncthreads();
    for (int s = 1; s < 256; s <<= 1) {
        int add = (t >= s) ? sm[t - s] : 0;
        __syncthreads();
        sm[t] += add;
        __syncthreads();
    }
    if (i < n) row_off[i] = chunkSums[c] + sm[t] - v;
}

// ---------------- two-pass bucketed scatter ----------------

__global__ void scatter_pass1(const int* __restrict__ row, const int* __restrict__ col,
                              const float* __restrict__ val,
                              const int* __restrict__ bucketOff, int* __restrict__ gcur,
                              int2* __restrict__ tmpE) {
    __shared__ int cnt[NB];
    __shared__ int base[NB];
    const int t = threadIdx.x;
    const int bs = blockIdx.x * EPB;
    const int be = min(N_EDGES, bs + EPB);
    for (int b = t; b < NB; b += 256) cnt[b] = 0;
    __syncthreads();
    for (int i = bs + t; i < be; i += 256) {
        atomicAdd(&cnt[row[i] >> 8], 1);
    }
    __syncthreads();
    for (int b = t; b < NB; b += 256) {
        int c = cnt[b];
        base[b] = bucketOff[b] + (c ? atomicAdd(&gcur[b], c) : 0);
        cnt[b] = 0;
    }
    __syncthreads();
    for (int i = bs + t; i < be; i += 256) {
        int r = row[i];
        int b = r >> 8;
        int pos = base[b] + atomicAdd(&cnt[b], 1);
        int2 e;
        e.x = (col[i] << 8) | (r & 255);
        e.y = __float_as_int(val[i]);
        tmpE[pos] = e;
    }
}

__global__ void scatter_pass2(const int2* __restrict__ tmpE, const int* __restrict__ bucketOff,
                              const int* __restrict__ row_off, int2* __restrict__ csr) {
    __shared__ int lcur[256];
    __shared__ int roff[256];
    const int b = blockIdx.x;
    const int t = threadIdx.x;
    const int rowBase = b << 8;
    const int gr = rowBase + t;
    lcur[t] = 0;
    roff[t] = (gr < N_NODES) ? row_off[gr] : 0;
    __syncthreads();
    const int segStart = bucketOff[b];
    const int segEnd = (b == NB - 1) ? N_EDGES : bucketOff[b + 1];
    for (int i = segStart + t; i < segEnd; i += 256) {
        int2 e = tmpE[i];
        int rl = e.x & 255;
        int pos = roff[rl] + atomicAdd(&lcur[rl], 1);
        int2 o;
        o.x = e.x >> 8;          // e.x < 2^25, positive
        o.y = e.y;
        csr[pos] = o;
    }
}

// ---------------- convert x -> bf16 segment of Ab ----------------

__global__ void convert_x(const float* __restrict__ x, ushort* __restrict__ Ab) {
    int gid = blockIdx.x * blockDim.x + threadIdx.x;       // one per 4 elems
    if (gid >= N_NODES * F_IN / 4) return;
    int li = gid * 4;
    int node = li >> 8;
    int c = li & 255;
    float4 v = *reinterpret_cast<const float4*>(&x[li]);
    ushort4 o;
    o.x = f2b(v.x); o.y = f2b(v.y); o.z = f2b(v.z); o.w = f2b(v.w);
    *reinterpret_cast<ushort4*>(&Ab[(size_t)node * K_TOT + c]) = o;
}

// ---------------- SpMM (bf16 in, bf16 out, fp32 accumulate) ----------------
// R4: 2 edges per gather slot. Lanes 0-31 read edge e0's h-row, lanes 32-63
// edge e1's; each lane loads ushort8 (16B dwordx4) = 8 features. 8 slots in
// flight = 16 edges / 8KB per wave (2x the R3 version's in-flight bytes at
// half the instruction count -- R3 measured 3.8 TB/s, latency-bound at
// VALUBusy 33%). CSR consumed as aligned int4 pairs (peel 1 edge if the row
// segment starts odd). Cross-half combine: 8x shfl_xor(32); lanes 0-31 write
// the 512B output row as ushort8.

__global__ void spmm_bf16(const int* __restrict__ row_off, const int2* __restrict__ csr,
                          const ushort* __restrict__ h, int hs,
                          ushort* __restrict__ y, int ys) {
    int wave = threadIdx.x >> 6;
    int lane = threadIdx.x & 63;
    int row = blockIdx.x * 4 + wave;
    if (row >= N_NODES) return;
    int s = row_off[row];
    int e = row_off[row + 1];
    const int half = lane >> 5;
    const int fl = lane & 31;
    const size_t foff = (size_t)fl * 8;

    float acc[8];
#pragma unroll
    for (int k = 0; k < 8; k++) acc[k] = 0.f;

    int j = s;
    // peel to even alignment so int4 CSR loads are 16B-aligned
    if ((j & 1) && j < e) {
        int2 e0 = csr[j];
        float v = half ? 0.f : __int_as_float(e0.y);
        ushortx8 g = *reinterpret_cast<const ushortx8*>(&h[(size_t)e0.x * hs + foff]);
#pragma unroll
        for (int k = 0; k < 8; k++) acc[k] += v * b2f((ushort)g[k]);
        j++;
    }
    for (; j + 16 <= e; j += 16) {
        int4 ee[8];
#pragma unroll
        for (int u = 0; u < 8; u++) ee[u] = *reinterpret_cast<const int4*>(&csr[j + 2 * u]);
        ushortx8 g[8];
#pragma unroll
        for (int u = 0; u < 8; u++) {
            int c = half ? ee[u].z : ee[u].x;
            g[u] = *reinterpret_cast<const ushortx8*>(&h[(size_t)c * hs + foff]);
        }
#pragma unroll
        for (int u = 0; u < 8; u++) {
            float v = __int_as_float(half ? ee[u].w : ee[u].y);
#pragma unroll
            for (int k = 0; k < 8; k++) acc[k] += v * b2f((ushort)g[u][k]);
        }
    }
    for (; j + 2 <= e; j += 2) {
        int4 ee = *reinterpret_cast<const int4*>(&csr[j]);
        int c = half ? ee.z : ee.x;
        float v = __int_as_float(half ? ee.w : ee.y);
        ushortx8 g = *reinterpret_cast<const ushortx8*>(&h[(size_t)c * hs + foff]);
#pragma unroll
        for (int k = 0; k < 8; k++) acc[k] += v * b2f((ushort)g[k]);
    }
    if (j < e) {
        int2 e0 = csr[j];
        float v = half ? 0.f : __int_as_float(e0.y);
        ushortx8 g = *reinterpret_cast<const ushortx8*>(&h[(size_t)e0.x * hs + foff]);
#pragma unroll
        for (int k = 0; k < 8; k++) acc[k] += v * b2f((ushort)g[k]);
    }

    // cross-half combine: lane l and l^32 hold partial sums of the same features
#pragma unroll
    for (int k = 0; k < 8; k++) acc[k] += __shfl_xor(acc[k], 32);

    if (half == 0) {
        ushortx8 o;
#pragma unroll
        for (int k = 0; k < 8; k++) o[k] = f2b(acc[k]);
        *reinterpret_cast<ushortx8*>(&y[(size_t)row * ys + foff]) = o;
    }
}

// ---------------- weight / BN prep ----------------
// Wt: bf16, K-major: Wt[n][kg], n in 0..511, kg in 0..1023
// kg seg 0 = sum_j w{a,b}_x[j]; seg s=1..3 = w{a,b}_adj[s-1]

__global__ void build_weights_t(const float* __restrict__ wa_x, const float* __restrict__ wa_adj,
                                const float* __restrict__ wb_x, const float* __restrict__ wb_adj,
                                ushort* __restrict__ Wt) {
    int idx = blockIdx.x * blockDim.x + threadIdx.x;
    if (idx >= M_OUT * K_TOT) return;
    int n = idx >> 10;        // 0..511
    int kg = idx & 1023;      // 0..1023
    int seg = kg >> 8;
    int k = kg & 255;
    float w;
    if (seg == 0) {
        if (n < 256)
            w = wa_x[0 * 65536 + k * 256 + n] + wa_x[1 * 65536 + k * 256 + n] + wa_x[2 * 65536 + k * 256 + n];
        else {
            int nn = n - 256;
            w = wb_x[0 * 65536 + k * 256 + nn] + wb_x[1 * 65536 + k * 256 + nn] + wb_x[2 * 65536 + k * 256 + nn];
        }
    } else {
        int s = seg - 1;
        if (n < 256) w = wa_adj[s * 65536 + k * 256 + n];
        else         w = wb_adj[s * 65536 + k * 256 + (n - 256)];
    }
    Wt[idx] = f2b(w);
}

__global__ void build_bn(const float* __restrict__ ga, const float* __restrict__ ba,
                         const float* __restrict__ ma, const float* __restrict__ va,
                         const float* __restrict__ gb, const float* __restrict__ bb,
                         const float* __restrict__ mb, const float* __restrict__ vb,
                         float* __restrict__ scale, float* __restrict__ bias) {
    int c = blockIdx.x * blockDim.x + threadIdx.x;
    if (c >= 512) return;
    float g, b, m, v;
    if (c < 256) { g = ga[c]; b = ba[c]; m = ma[c]; v = va[c]; }
    else { int cc = c - 256; g = gb[cc]; b = bb[cc]; m = mb[cc]; v = vb[cc]; }
    float s = g / sqrtf(v + EPS_BN);
    scale[c] = s;
    bias[c] = b - m * s;
}

// ---------------- MFMA GEMM: C[N,512] = Ab[N,1024] @ Wt^T, fused relu+BN ----------------
// block = 256 threads = 4 waves (2x2), block tile 128x128, wave tile 64x64
// Ab row-major [m][k]; Wt K-major [n][k]  =>  both staged identically.
// LDS stride 40 elems (80 B): rows hit banks with period 8 -> 2-way (free).

#define LDS_STRIDE 40

__global__ void gemm_mfma(const ushort* __restrict__ Ab, const ushort* __restrict__ Wt,
                          float* __restrict__ C,
                          const float* __restrict__ scale, const float* __restrict__ bias) {
    __shared__ ushort As[128 * LDS_STRIDE];
    __shared__ ushort Bs[128 * LDS_STRIDE];
    const int tid = threadIdx.x;
    const int lane = tid & 63;
    const int wave = tid >> 6;
    const int wm = wave >> 1;       // wave row half (0/1)
    const int wn = wave & 1;        // wave col half (0/1)
    const int quad = lane >> 4;
    const int l16 = lane & 15;
    const int mBase = blockIdx.y * 128;
    const int nBase = blockIdx.x * 128;

    floatx4 acc[4][4];
#pragma unroll
    for (int i = 0; i < 4; i++)
#pragma unroll
        for (int j = 0; j < 4; j++) acc[i][j] = (floatx4){0.f, 0.f, 0.f, 0.f};

    for (int k0 = 0; k0 < K_TOT; k0 += 32) {
        // stage A and B tiles: 128 rows x 32 cols bf16 each
#pragma unroll
        for (int p = 0; p < 2; p++) {
            int li = tid + p * 256;
            int row = li >> 2;             // 0..127
            int c8 = (li & 3) * 8;         // 0,8,16,24
            int gm = mBase + row; if (gm > N_NODES - 1) gm = N_NODES - 1;
            uint4 va = *reinterpret_cast<const uint4*>(&Ab[(size_t)gm * K_TOT + k0 + c8]);
            uint4 vb = *reinterpret_cast<const uint4*>(&Wt[(size_t)(nBase + row) * K_TOT + k0 + c8]);
            *reinterpret_cast<uint4*>(&As[row * LDS_STRIDE + c8]) = va;
            *reinterpret_cast<uint4*>(&Bs[row * LDS_STRIDE + c8]) = vb;
        }
        __syncthreads();

        short8 a_frag[4], b_frag[4];
#pragma unroll
        for (int i = 0; i < 4; i++)
            a_frag[i] = *reinterpret_cast<const short8*>(&As[(wm * 64 + i * 16 + l16) * LDS_STRIDE + quad * 8]);
#pragma unroll
        for (int j = 0; j < 4; j++)
            b_frag[j] = *reinterpret_cast<const short8*>(&Bs[(wn * 64 + j * 16 + l16) * LDS_STRIDE + quad * 8]);
#pragma unroll
        for (int i = 0; i < 4; i++)
#pragma unroll
            for (int j = 0; j < 4; j++)
                acc[i][j] = __builtin_amdgcn_mfma_f32_16x16x32_bf16(a_frag[i], b_frag[j], acc[i][j], 0, 0, 0);
        __syncthreads();
    }

    // epilogue: relu on cols < 256, then BN affine; C row-major [m][512]
    float sc[4], bs[4];
    int gncol[4];
#pragma unroll
    for (int j = 0; j < 4; j++) {
        int gn = nBase + wn * 64 + j * 16 + l16;
        gncol[j] = gn;
        sc[j] = scale[gn];
        bs[j] = bias[gn];
    }
#pragma unroll
    for (int i = 0; i < 4; i++) {
#pragma unroll
        for (int r = 0; r < 4; r++) {
            int gm = mBase + wm * 64 + i * 16 + quad * 4 + r;
            if (gm >= N_NODES) continue;
#pragma unroll
            for (int j = 0; j < 4; j++) {
                float v = acc[i][j][r];
                if (gncol[j] < 256) v = fmaxf(v, 0.f);
                v = v * sc[j] + bs[j];
                C[(size_t)gm * M_OUT + gncol[j]] = v;
            }
        }
    }
}

// ---------------- launch ----------------

static inline size_t align_up(size_t x, size_t a) { return (x + a - 1) & ~(a - 1); }

extern "C" void kernel_launch(void* const* d_in, const int* in_sizes, int n_in,
                              void* d_out, int out_size, void* d_ws, size_t ws_size,
                              hipStream_t stream) {
    const float* x      = (const float*)d_in[0];
    const int*   erow   = (const int*)d_in[1];
    const int*   ecol   = (const int*)d_in[2];
    const float* eval   = (const float*)d_in[3];
    const float* wa_x   = (const float*)d_in[4];
    const float* wa_adj = (const float*)d_in[5];
    const float* wb_x   = (const float*)d_in[6];
    const float* wb_adj = (const float*)d_in[7];
    const float* ga = (const float*)d_in[8];
    const float* ba = (const float*)d_in[9];
    const float* ma = (const float*)d_in[10];
    const float* va = (const float*)d_in[11];
    const float* gb = (const float*)d_in[12];
    const float* bb = (const float*)d_in[13];
    const float* mb = (const float*)d_in[14];
    const float* vb = (const float*)d_in[15];
    float* out = (float*)d_out;

    char* ws = (char*)d_ws;
    size_t off = 0;
    int*    row_off   = (int*)(ws + off);    off = align_up(off + (size_t)(N_NODES + 1) * 4, 1024);
    int*    cursor    = (int*)(ws + off);    off = align_up(off + (size_t)N_NODES * 4, 1024);
    int*    chunkSums = (int*)(ws + off);    off = align_up(off + (size_t)NUM_CHUNKS * 4, 1024);
    int2*   csr       = (int2*)(ws + off);   off = align_up(off + (size_t)N_EDGES * 8, 1024);
    ushort* Wt        = (ushort*)(ws + off); off = align_up(off + (size_t)M_OUT * K_TOT * 2, 1024);
    float*  scale     = (float*)(ws + off);  off = align_up(off + 512 * 4, 1024);
    float*  bias      = (float*)(ws + off);  off = align_up(off + 512 * 4, 1024);
    ushort* Ab        = (ushort*)(ws + off); off = align_up(off + (size_t)N_NODES * K_TOT * 2, 1024);
    ushort* tmp       = (ushort*)(ws + off); off = align_up(off + (size_t)N_NODES * F_IN * 2, 1024);
    // pass-1 temp edge buffer aliases the hop scratch (stream-serial: pass1/pass2
    // complete before the spmm chain touches tmp). 25.6MB <= 51.2MB.
    int2*   tmpE      = (int2*)tmp;
    (void)ws_size; (void)in_sizes; (void)n_in; (void)out_size;

    const int zeroBlocks = (N_NODES + 255) / 256;
    const int edgeBlocks = (N_EDGES + 255) / 256;
    const int p1Blocks = (N_EDGES + EPB - 1) / EPB;

    // ---- CSR build ----
    zero_i32<<<zeroBlocks, 256, 0, stream>>>(cursor, N_NODES);
    hist_kernel<<<edgeBlocks, 256, 0, stream>>>(erow, cursor, N_EDGES);
    scan_chunk_sums<<<NUM_CHUNKS, 256, 0, stream>>>(cursor, chunkSums, N_NODES);
    scan_spine<<<1, 512, 0, stream>>>(chunkSums, NUM_CHUNKS, row_off, N_NODES);
    scan_final<<<NUM_CHUNKS, 256, 0, stream>>>(cursor, chunkSums, row_off, N_NODES);
    // reuse cursor[0..NB) as per-bucket global cursors
    zero_i32<<<(NB + 255) / 256, 256, 0, stream>>>(cursor, NB);
    scatter_pass1<<<p1Blocks, 256, 0, stream>>>(erow, ecol, eval, chunkSums, cursor, tmpE);
    scatter_pass2<<<NB, 256, 0, stream>>>(tmpE, chunkSums, row_off, csr);

    // ---- weight & BN prep ----
    build_weights_t<<<(M_OUT * K_TOT) / 256, 256, 0, stream>>>(wa_x, wa_adj, wb_x, wb_adj, Wt);
    build_bn<<<2, 256, 0, stream>>>(ga, ba, ma, va, gb, bb, mb, vb, scale, bias);

    // ---- x -> bf16 (segment 0 of Ab) ----
    convert_x<<<(N_NODES * F_IN / 4 + 255) / 256, 256, 0, stream>>>(x, Ab);

    // ---- hop chain (bf16 storage, fp32 accumulate) ----
    const int spmmBlocks = (N_NODES + 3) / 4;
    spmm_bf16<<<spmmBlocks, 256, 0, stream>>>(row_off, csr,
                                              Ab + 0 * 256, K_TOT, Ab + 1 * 256, K_TOT);   // A x
    spmm_bf16<<<spmmBlocks, 256, 0, stream>>>(row_off, csr,
                                              Ab + 1 * 256, K_TOT, Ab + 2 * 256, K_TOT);   // A^2 x
    spmm_bf16<<<spmmBlocks, 256, 0, stream>>>(row_off, csr,
                                              Ab + 2 * 256, K_TOT, tmp, F_IN);             // A^3 x
    spmm_bf16<<<spmmBlocks, 256, 0, stream>>>(row_off, csr,
                                              tmp, F_IN, Ab + 3 * 256, K_TOT);             // A^4 x

    // ---- fused GEMM + relu + BN ----
    dim3 gemmGrid(M_OUT / 128, (N_NODES + 127) / 128);
    gemm_mfma<<<gemmGrid, 256, 0, stream>>>(Ab, Wt, out, scale, bias);
}

// Round 3
// 1584.998 us; speedup vs baseline: 1.5875x; 1.5875x over previous
//
#include <hip/hip_runtime.h>
#include <math.h>

#define N_NODES 100000
#define N_EDGES 3200000
#define F_IN 256
#define M_OUT 512            // 2*F_OUT concat
#define K_TOT 1024           // [x | Ax | A^2x | A^4x]
#define EPS_BN 1e-3f
#define NUM_CHUNKS 391       // ceil(100000/256) == number of row buckets
#define NB NUM_CHUNKS
#define EPB 16384            // edges per block in scatter pass 1

typedef __attribute__((ext_vector_type(8))) short short8;
typedef __attribute__((ext_vector_type(8))) ushort ushortx8;
typedef __attribute__((ext_vector_type(4))) float floatx4;

__device__ __forceinline__ ushort f2b(float f) {
    union { float f; unsigned u; } c; c.f = f;
    unsigned u = c.u;
    unsigned r = (u + 0x7FFFu + ((u >> 16) & 1u)) >> 16;   // RNE
    return (ushort)r;
}
__device__ __forceinline__ float b2f(ushort b) {
    union { unsigned u; float f; } c; c.u = ((unsigned)b) << 16;
    return c.f;
}

// ---------------- small utility kernels ----------------

__global__ void zero_i32(int* __restrict__ p, int n) {
    int i = blockIdx.x * blockDim.x + threadIdx.x;
    if (i < n) p[i] = 0;
}

__global__ void hist_kernel(const int* __restrict__ row, int* __restrict__ counts, int n) {
    int i = blockIdx.x * blockDim.x + threadIdx.x;
    if (i < n) atomicAdd(&counts[row[i]], 1);
}

__global__ void scan_chunk_sums(const int* __restrict__ counts, int* __restrict__ chunkSums, int n) {
    __shared__ int sm[256];
    int c = blockIdx.x;
    int t = threadIdx.x;
    int i = c * 256 + t;
    sm[t] = (i < n) ? counts[i] : 0;
    __syncthreads();
    for (int s = 128; s > 0; s >>= 1) {
        if (t < s) sm[t] += sm[t + s];
        __syncthreads();
    }
    if (t == 0) chunkSums[c] = sm[0];
}

__global__ void scan_spine(int* __restrict__ chunkSums, int numChunks, int* __restrict__ row_off, int n) {
    __shared__ int sm[512];
    int t = threadIdx.x;
    int v = (t < numChunks) ? chunkSums[t] : 0;
    sm[t] = v;
    __syncthreads();
    for (int s = 1; s < 512; s <<= 1) {
        int add = (t >= s) ? sm[t - s] : 0;
        __syncthreads();
        sm[t] += add;
        __syncthreads();
    }
    if (t < numChunks) chunkSums[t] = sm[t] - v;   // exclusive: bucket start offsets
    if (t == 511) row_off[n] = sm[511];
}

__global__ void scan_final(const int* __restrict__ counts, const int* __restrict__ chunkSums,
                           int* __restrict__ row_off, int n) {
    __shared__ int sm[256];
    int c = blockIdx.x;
    int t = threadIdx.x;
    int i = c * 256 + t;
    int v = (i < n) ? counts[i] : 0;
    sm[t] = v;
    __syncthreads();
    for (int s = 1; s < 256; s <<= 1) {
        int add = (t >= s) ? sm[t - s] : 0;
        __syncthreads();
        sm[t] += add;
        __syncthreads();
    }
    if (i < n) row_off[i] = chunkSums[c] + sm[t] - v;
}

// ---------------- two-pass bucketed scatter ----------------

__global__ void scatter_pass1(const int* __restrict__ row, const int* __restrict__ col,
                              const float* __restrict__ val,
                              const int* __restrict__ bucketOff, int* __restrict__ gcur,
                              int2* __restrict__ tmpE) {
    __shared__ int cnt[NB];
    __shared__ int base[NB];
    const int t = threadIdx.x;
    const int bs = blockIdx.x * EPB;
    const int be = min(N_EDGES, bs + EPB);
    for (int b = t; b < NB; b += 256) cnt[b] = 0;
    __syncthreads();
    for (int i = bs + t; i < be; i += 256) {
        atomicAdd(&cnt[row[i] >> 8], 1);
    }
    __syncthreads();
    for (int b = t; b < NB; b += 256) {
        int c = cnt[b];
        base[b] = bucketOff[b] + (c ? atomicAdd(&gcur[b], c) : 0);
        cnt[b] = 0;
    }
    __syncthreads();
    for (int i = bs + t; i < be; i += 256) {
        int r = row[i];
        int b = r >> 8;
        int pos = base[b] + atomicAdd(&cnt[b], 1);
        int2 e;
        e.x = (col[i] << 8) | (r & 255);
        e.y = __float_as_int(val[i]);
        tmpE[pos] = e;
    }
}

__global__ void scatter_pass2(const int2* __restrict__ tmpE, const int* __restrict__ bucketOff,
                              const int* __restrict__ row_off, int2* __restrict__ csr) {
    __shared__ int lcur[256];
    __shared__ int roff[256];
    const int b = blockIdx.x;
    const int t = threadIdx.x;
    const int rowBase = b << 8;
    const int gr = rowBase + t;
    lcur[t] = 0;
    roff[t] = (gr < N_NODES) ? row_off[gr] : 0;
    __syncthreads();
    const int segStart = bucketOff[b];
    const int segEnd = (b == NB - 1) ? N_EDGES : bucketOff[b + 1];
    for (int i = segStart + t; i < segEnd; i += 256) {
        int2 e = tmpE[i];
        int rl = e.x & 255;
        int pos = roff[rl] + atomicAdd(&lcur[rl], 1);
        int2 o;
        o.x = e.x >> 8;          // e.x < 2^25, positive
        o.y = e.y;
        csr[pos] = o;
    }
}

// ---------------- convert x -> bf16 segment of Ab ----------------

__global__ void convert_x(const float* __restrict__ x, ushort* __restrict__ Ab) {
    int gid = blockIdx.x * blockDim.x + threadIdx.x;       // one per 4 elems
    if (gid >= N_NODES * F_IN / 4) return;
    int li = gid * 4;
    int node = li >> 8;
    int c = li & 255;
    float4 v = *reinterpret_cast<const float4*>(&x[li]);
    ushort4 o;
    o.x = f2b(v.x); o.y = f2b(v.y); o.z = f2b(v.z); o.w = f2b(v.w);
    *reinterpret_cast<ushort4*>(&Ab[(size_t)node * K_TOT + c]) = o;
}

// ---------------- SpMM (bf16 in, bf16 out, fp32 accumulate) ----------------
// R5: R4's WRITE_SIZE exploded 50MB->1.24GB = scratch spill (int4 ee[8] +
// ushortx8 g[8] arrays need 64+ live VGPRs; allocator stuck at 40 -> arrays
// demoted to scratch; ~1.6GB spill stores/dispatch). Fix: depth-4 slots with
// NAMED registers (e0..e3 / g0..g3, nothing array-indexed), plus
// __launch_bounds__(256,2) to grant a 256-VGPR budget so the occupancy
// heuristic doesn't spill. Still 2 edges per slot: lanes 0-31 gather edge
// e_even's h-row, lanes 32-63 e_odd's, 16B (8 feats) per lane. In-flight
// 4KB/wave (= R3) at half R3's memory-instruction count.

__global__ void __launch_bounds__(256, 2)
spmm_bf16(const int* __restrict__ row_off, const int2* __restrict__ csr,
          const ushort* __restrict__ h, int hs,
          ushort* __restrict__ y, int ys) {
    int wave = threadIdx.x >> 6;
    int lane = threadIdx.x & 63;
    int row = blockIdx.x * 4 + wave;
    if (row >= N_NODES) return;
    int s = row_off[row];
    int e = row_off[row + 1];
    const int half = lane >> 5;
    const int fl = lane & 31;
    const size_t foff = (size_t)fl * 8;

    float acc[8];
#pragma unroll
    for (int k = 0; k < 8; k++) acc[k] = 0.f;

    int j = s;
    // peel to even alignment so int4 CSR loads are 16B-aligned
    if ((j & 1) && j < e) {
        int2 e0 = csr[j];
        float v = half ? 0.f : __int_as_float(e0.y);
        ushortx8 g = *reinterpret_cast<const ushortx8*>(&h[(size_t)e0.x * hs + foff]);
#pragma unroll
        for (int k = 0; k < 8; k++) acc[k] += v * b2f((ushort)g[k]);
        j++;
    }

#define CSR_LD(dst, idx) int4 dst = *reinterpret_cast<const int4*>(&csr[j + 2 * (idx)])
#define GATHER(gdst, ee) ushortx8 gdst = *reinterpret_cast<const ushortx8*>( \
        &h[(size_t)(half ? (ee).z : (ee).x) * hs + foff])
#define CONSUME(gg, ee) { float v_ = __int_as_float(half ? (ee).w : (ee).y); \
        _Pragma("unroll") for (int k = 0; k < 8; k++) acc[k] += v_ * b2f((ushort)(gg)[k]); }

    for (; j + 8 <= e; j += 8) {
        CSR_LD(e0, 0); CSR_LD(e1, 1); CSR_LD(e2, 2); CSR_LD(e3, 3);
        GATHER(g0, e0); GATHER(g1, e1); GATHER(g2, e2); GATHER(g3, e3);
        CONSUME(g0, e0); CONSUME(g1, e1); CONSUME(g2, e2); CONSUME(g3, e3);
    }
    for (; j + 2 <= e; j += 2) {
        CSR_LD(e0, 0);
        GATHER(g0, e0);
        CONSUME(g0, e0);
    }
    if (j < e) {
        int2 e0 = csr[j];
        float v = half ? 0.f : __int_as_float(e0.y);
        ushortx8 g = *reinterpret_cast<const ushortx8*>(&h[(size_t)e0.x * hs + foff]);
#pragma unroll
        for (int k = 0; k < 8; k++) acc[k] += v * b2f((ushort)g[k]);
    }
#undef CSR_LD
#undef GATHER
#undef CONSUME

    // cross-half combine: lane l and l^32 hold partial sums of the same features
#pragma unroll
    for (int k = 0; k < 8; k++) acc[k] += __shfl_xor(acc[k], 32);

    if (half == 0) {
        ushortx8 o;
#pragma unroll
        for (int k = 0; k < 8; k++) o[k] = f2b(acc[k]);
        *reinterpret_cast<ushortx8*>(&y[(size_t)row * ys + foff]) = o;
    }
}

// ---------------- weight / BN prep ----------------
// Wt: bf16, K-major: Wt[n][kg], n in 0..511, kg in 0..1023
// kg seg 0 = sum_j w{a,b}_x[j]; seg s=1..3 = w{a,b}_adj[s-1]

__global__ void build_weights_t(const float* __restrict__ wa_x, const float* __restrict__ wa_adj,
                                const float* __restrict__ wb_x, const float* __restrict__ wb_adj,
                                ushort* __restrict__ Wt) {
    int idx = blockIdx.x * blockDim.x + threadIdx.x;
    if (idx >= M_OUT * K_TOT) return;
    int n = idx >> 10;        // 0..511
    int kg = idx & 1023;      // 0..1023
    int seg = kg >> 8;
    int k = kg & 255;
    float w;
    if (seg == 0) {
        if (n < 256)
            w = wa_x[0 * 65536 + k * 256 + n] + wa_x[1 * 65536 + k * 256 + n] + wa_x[2 * 65536 + k * 256 + n];
        else {
            int nn = n - 256;
            w = wb_x[0 * 65536 + k * 256 + nn] + wb_x[1 * 65536 + k * 256 + nn] + wb_x[2 * 65536 + k * 256 + nn];
        }
    } else {
        int s = seg - 1;
        if (n < 256) w = wa_adj[s * 65536 + k * 256 + n];
        else         w = wb_adj[s * 65536 + k * 256 + (n - 256)];
    }
    Wt[idx] = f2b(w);
}

__global__ void build_bn(const float* __restrict__ ga, const float* __restrict__ ba,
                         const float* __restrict__ ma, const float* __restrict__ va,
                         const float* __restrict__ gb, const float* __restrict__ bb,
                         const float* __restrict__ mb, const float* __restrict__ vb,
                         float* __restrict__ scale, float* __restrict__ bias) {
    int c = blockIdx.x * blockDim.x + threadIdx.x;
    if (c >= 512) return;
    float g, b, m, v;
    if (c < 256) { g = ga[c]; b = ba[c]; m = ma[c]; v = va[c]; }
    else { int cc = c - 256; g = gb[cc]; b = bb[cc]; m = mb[cc]; v = vb[cc]; }
    float s = g / sqrtf(v + EPS_BN);
    scale[c] = s;
    bias[c] = b - m * s;
}

// ---------------- MFMA GEMM: C[N,512] = Ab[N,1024] @ Wt^T, fused relu+BN ----------------
// block = 256 threads = 4 waves (2x2), block tile 128x128, wave tile 64x64
// Ab row-major [m][k]; Wt K-major [n][k]  =>  both staged identically.
// LDS stride 40 elems (80 B): rows hit banks with period 8 -> 2-way (free).

#define LDS_STRIDE 40

__global__ void gemm_mfma(const ushort* __restrict__ Ab, const ushort* __restrict__ Wt,
                          float* __restrict__ C,
                          const float* __restrict__ scale, const float* __restrict__ bias) {
    __shared__ ushort As[128 * LDS_STRIDE];
    __shared__ ushort Bs[128 * LDS_STRIDE];
    const int tid = threadIdx.x;
    const int lane = tid & 63;
    const int wave = tid >> 6;
    const int wm = wave >> 1;       // wave row half (0/1)
    const int wn = wave & 1;        // wave col half (0/1)
    const int quad = lane >> 4;
    const int l16 = lane & 15;
    const int mBase = blockIdx.y * 128;
    const int nBase = blockIdx.x * 128;

    floatx4 acc[4][4];
#pragma unroll
    for (int i = 0; i < 4; i++)
#pragma unroll
        for (int j = 0; j < 4; j++) acc[i][j] = (floatx4){0.f, 0.f, 0.f, 0.f};

    for (int k0 = 0; k0 < K_TOT; k0 += 32) {
        // stage A and B tiles: 128 rows x 32 cols bf16 each
#pragma unroll
        for (int p = 0; p < 2; p++) {
            int li = tid + p * 256;
            int row = li >> 2;             // 0..127
            int c8 = (li & 3) * 8;         // 0,8,16,24
            int gm = mBase + row; if (gm > N_NODES - 1) gm = N_NODES - 1;
            uint4 va = *reinterpret_cast<const uint4*>(&Ab[(size_t)gm * K_TOT + k0 + c8]);
            uint4 vb = *reinterpret_cast<const uint4*>(&Wt[(size_t)(nBase + row) * K_TOT + k0 + c8]);
            *reinterpret_cast<uint4*>(&As[row * LDS_STRIDE + c8]) = va;
            *reinterpret_cast<uint4*>(&Bs[row * LDS_STRIDE + c8]) = vb;
        }
        __syncthreads();

        short8 a_frag[4], b_frag[4];
#pragma unroll
        for (int i = 0; i < 4; i++)
            a_frag[i] = *reinterpret_cast<const short8*>(&As[(wm * 64 + i * 16 + l16) * LDS_STRIDE + quad * 8]);
#pragma unroll
        for (int j = 0; j < 4; j++)
            b_frag[j] = *reinterpret_cast<const short8*>(&Bs[(wn * 64 + j * 16 + l16) * LDS_STRIDE + quad * 8]);
#pragma unroll
        for (int i = 0; i < 4; i++)
#pragma unroll
            for (int j = 0; j < 4; j++)
                acc[i][j] = __builtin_amdgcn_mfma_f32_16x16x32_bf16(a_frag[i], b_frag[j], acc[i][j], 0, 0, 0);
        __syncthreads();
    }

    // epilogue: relu on cols < 256, then BN affine; C row-major [m][512]
    float sc[4], bs[4];
    int gncol[4];
#pragma unroll
    for (int j = 0; j < 4; j++) {
        int gn = nBase + wn * 64 + j * 16 + l16;
        gncol[j] = gn;
        sc[j] = scale[gn];
        bs[j] = bias[gn];
    }
#pragma unroll
    for (int i = 0; i < 4; i++) {
#pragma unroll
        for (int r = 0; r < 4; r++) {
            int gm = mBase + wm * 64 + i * 16 + quad * 4 + r;
            if (gm >= N_NODES) continue;
#pragma unroll
            for (int j = 0; j < 4; j++) {
                float v = acc[i][j][r];
                if (gncol[j] < 256) v = fmaxf(v, 0.f);
                v = v * sc[j] + bs[j];
                C[(size_t)gm * M_OUT + gncol[j]] = v;
            }
        }
    }
}

// ---------------- launch ----------------

static inline size_t align_up(size_t x, size_t a) { return (x + a - 1) & ~(a - 1); }

extern "C" void kernel_launch(void* const* d_in, const int* in_sizes, int n_in,
                              void* d_out, int out_size, void* d_ws, size_t ws_size,
                              hipStream_t stream) {
    const float* x      = (const float*)d_in[0];
    const int*   erow   = (const int*)d_in[1];
    const int*   ecol   = (const int*)d_in[2];
    const float* eval   = (const float*)d_in[3];
    const float* wa_x   = (const float*)d_in[4];
    const float* wa_adj = (const float*)d_in[5];
    const float* wb_x   = (const float*)d_in[6];
    const float* wb_adj = (const float*)d_in[7];
    const float* ga = (const float*)d_in[8];
    const float* ba = (const float*)d_in[9];
    const float* ma = (const float*)d_in[10];
    const float* va = (const float*)d_in[11];
    const float* gb = (const float*)d_in[12];
    const float* bb = (const float*)d_in[13];
    const float* mb = (const float*)d_in[14];
    const float* vb = (const float*)d_in[15];
    float* out = (float*)d_out;

    char* ws = (char*)d_ws;
    size_t off = 0;
    int*    row_off   = (int*)(ws + off);    off = align_up(off + (size_t)(N_NODES + 1) * 4, 1024);
    int*    cursor    = (int*)(ws + off);    off = align_up(off + (size_t)N_NODES * 4, 1024);
    int*    chunkSums = (int*)(ws + off);    off = align_up(off + (size_t)NUM_CHUNKS * 4, 1024);
    int2*   csr       = (int2*)(ws + off);   off = align_up(off + (size_t)N_EDGES * 8, 1024);
    ushort* Wt        = (ushort*)(ws + off); off = align_up(off + (size_t)M_OUT * K_TOT * 2, 1024);
    float*  scale     = (float*)(ws + off);  off = align_up(off + 512 * 4, 1024);
    float*  bias      = (float*)(ws + off);  off = align_up(off + 512 * 4, 1024);
    ushort* Ab        = (ushort*)(ws + off); off = align_up(off + (size_t)N_NODES * K_TOT * 2, 1024);
    ushort* tmp       = (ushort*)(ws + off); off = align_up(off + (size_t)N_NODES * F_IN * 2, 1024);
    // pass-1 temp edge buffer aliases the hop scratch (stream-serial: pass1/pass2
    // complete before the spmm chain touches tmp). 25.6MB <= 51.2MB.
    int2*   tmpE      = (int2*)tmp;
    (void)ws_size; (void)in_sizes; (void)n_in; (void)out_size;

    const int zeroBlocks = (N_NODES + 255) / 256;
    const int edgeBlocks = (N_EDGES + 255) / 256;
    const int p1Blocks = (N_EDGES + EPB - 1) / EPB;

    // ---- CSR build ----
    zero_i32<<<zeroBlocks, 256, 0, stream>>>(cursor, N_NODES);
    hist_kernel<<<edgeBlocks, 256, 0, stream>>>(erow, cursor, N_EDGES);
    scan_chunk_sums<<<NUM_CHUNKS, 256, 0, stream>>>(cursor, chunkSums, N_NODES);
    scan_spine<<<1, 512, 0, stream>>>(chunkSums, NUM_CHUNKS, row_off, N_NODES);
    scan_final<<<NUM_CHUNKS, 256, 0, stream>>>(cursor, chunkSums, row_off, N_NODES);
    // reuse cursor[0..NB) as per-bucket global cursors
    zero_i32<<<(NB + 255) / 256, 256, 0, stream>>>(cursor, NB);
    scatter_pass1<<<p1Blocks, 256, 0, stream>>>(erow, ecol, eval, chunkSums, cursor, tmpE);
    scatter_pass2<<<NB, 256, 0, stream>>>(tmpE, chunkSums, row_off, csr);

    // ---- weight & BN prep ----
    build_weights_t<<<(M_OUT * K_TOT) / 256, 256, 0, stream>>>(wa_x, wa_adj, wb_x, wb_adj, Wt);
    build_bn<<<2, 256, 0, stream>>>(ga, ba, ma, va, gb, bb, mb, vb, scale, bias);

    // ---- x -> bf16 (segment 0 of Ab) ----
    convert_x<<<(N_NODES * F_IN / 4 + 255) / 256, 256, 0, stream>>>(x, Ab);

    // ---- hop chain (bf16 storage, fp32 accumulate) ----
    const int spmmBlocks = (N_NODES + 3) / 4;
    spmm_bf16<<<spmmBlocks, 256, 0, stream>>>(row_off, csr,
                                              Ab + 0 * 256, K_TOT, Ab + 1 * 256, K_TOT);   // A x
    spmm_bf16<<<spmmBlocks, 256, 0, stream>>>(row_off, csr,
                                              Ab + 1 * 256, K_TOT, Ab + 2 * 256, K_TOT);   // A^2 x
    spmm_bf16<<<spmmBlocks, 256, 0, stream>>>(row_off, csr,
                                              Ab + 2 * 256, K_TOT, tmp, F_IN);             // A^3 x
    spmm_bf16<<<spmmBlocks, 256, 0, stream>>>(row_off, csr,
                                              tmp, F_IN, Ab + 3 * 256, K_TOT);             // A^4 x

    // ---- fused GEMM + relu + BN ----
    dim3 gemmGrid(M_OUT / 128, (N_NODES + 127) / 128);
    gemm_mfma<<<gemmGrid, 256, 0, stream>>>(Ab, Wt, out, scale, bias);
}

// Round 4
// 1573.871 us; speedup vs baseline: 1.5987x; 1.0071x over previous
//
#include <hip/hip_runtime.h>
#include <math.h>

#define N_NODES 100000
#define N_EDGES 3200000
#define F_IN 256
#define M_OUT 512            // 2*F_OUT concat
#define K_TOT 1024           // [x | Ax | A^2x | A^4x]
#define EPS_BN 1e-3f
#define NUM_CHUNKS 391       // ceil(100000/256) == number of row buckets
#define NB NUM_CHUNKS
#define EPB 16384            // edges per block in scatter pass 1

typedef __attribute__((ext_vector_type(8))) short short8;
typedef __attribute__((ext_vector_type(8))) ushort ushortx8;
typedef __attribute__((ext_vector_type(4))) float floatx4;

__device__ __forceinline__ ushort f2b(float f) {
    union { float f; unsigned u; } c; c.f = f;
    unsigned u = c.u;
    unsigned r = (u + 0x7FFFu + ((u >> 16) & 1u)) >> 16;   // RNE
    return (ushort)r;
}
__device__ __forceinline__ float b2f(ushort b) {
    union { unsigned u; float f; } c; c.u = ((unsigned)b) << 16;
    return c.f;
}

// ---------------- small utility kernels ----------------

__global__ void zero_i32(int* __restrict__ p, int n) {
    int i = blockIdx.x * blockDim.x + threadIdx.x;
    if (i < n) p[i] = 0;
}

__global__ void hist_kernel(const int* __restrict__ row, int* __restrict__ counts, int n) {
    int i = blockIdx.x * blockDim.x + threadIdx.x;
    if (i < n) atomicAdd(&counts[row[i]], 1);
}

__global__ void scan_chunk_sums(const int* __restrict__ counts, int* __restrict__ chunkSums, int n) {
    __shared__ int sm[256];
    int c = blockIdx.x;
    int t = threadIdx.x;
    int i = c * 256 + t;
    sm[t] = (i < n) ? counts[i] : 0;
    __syncthreads();
    for (int s = 128; s > 0; s >>= 1) {
        if (t < s) sm[t] += sm[t + s];
        __syncthreads();
    }
    if (t == 0) chunkSums[c] = sm[0];
}

__global__ void scan_spine(int* __restrict__ chunkSums, int numChunks, int* __restrict__ row_off, int n) {
    __shared__ int sm[512];
    int t = threadIdx.x;
    int v = (t < numChunks) ? chunkSums[t] : 0;
    sm[t] = v;
    __syncthreads();
    for (int s = 1; s < 512; s <<= 1) {
        int add = (t >= s) ? sm[t - s] : 0;
        __syncthreads();
        sm[t] += add;
        __syncthreads();
    }
    if (t < numChunks) chunkSums[t] = sm[t] - v;   // exclusive: bucket start offsets
    if (t == 511) row_off[n] = sm[511];
}

__global__ void scan_final(const int* __restrict__ counts, const int* __restrict__ chunkSums,
                           int* __restrict__ row_off, int n) {
    __shared__ int sm[256];
    int c = blockIdx.x;
    int t = threadIdx.x;
    int i = c * 256 + t;
    int v = (i < n) ? counts[i] : 0;
    sm[t] = v;
    __syncthreads();
    for (int s = 1; s < 256; s <<= 1) {
        int add = (t >= s) ? sm[t - s] : 0;
        __syncthreads();
        sm[t] += add;
        __syncthreads();
    }
    if (i < n) row_off[i] = chunkSums[c] + sm[t] - v;
}

// ---------------- two-pass bucketed scatter ----------------

__global__ void scatter_pass1(const int* __restrict__ row, const int* __restrict__ col,
                              const float* __restrict__ val,
                              const int* __restrict__ bucketOff, int* __restrict__ gcur,
                              int2* __restrict__ tmpE) {
    __shared__ int cnt[NB];
    __shared__ int base[NB];
    const int t = threadIdx.x;
    const int bs = blockIdx.x * EPB;
    const int be = min(N_EDGES, bs + EPB);
    for (int b = t; b < NB; b += 256) cnt[b] = 0;
    __syncthreads();
    for (int i = bs + t; i < be; i += 256) {
        atomicAdd(&cnt[row[i] >> 8], 1);
    }
    __syncthreads();
    for (int b = t; b < NB; b += 256) {
        int c = cnt[b];
        base[b] = bucketOff[b] + (c ? atomicAdd(&gcur[b], c) : 0);
        cnt[b] = 0;
    }
    __syncthreads();
    for (int i = bs + t; i < be; i += 256) {
        int r = row[i];
        int b = r >> 8;
        int pos = base[b] + atomicAdd(&cnt[b], 1);
        int2 e;
        e.x = (col[i] << 8) | (r & 255);
        e.y = __float_as_int(val[i]);
        tmpE[pos] = e;
    }
}

__global__ void scatter_pass2(const int2* __restrict__ tmpE, const int* __restrict__ bucketOff,
                              const int* __restrict__ row_off, int2* __restrict__ csr) {
    __shared__ int lcur[256];
    __shared__ int roff[256];
    const int b = blockIdx.x;
    const int t = threadIdx.x;
    const int rowBase = b << 8;
    const int gr = rowBase + t;
    lcur[t] = 0;
    roff[t] = (gr < N_NODES) ? row_off[gr] : 0;
    __syncthreads();
    const int segStart = bucketOff[b];
    const int segEnd = (b == NB - 1) ? N_EDGES : bucketOff[b + 1];
    for (int i = segStart + t; i < segEnd; i += 256) {
        int2 e = tmpE[i];
        int rl = e.x & 255;
        int pos = roff[rl] + atomicAdd(&lcur[rl], 1);
        int2 o;
        o.x = e.x >> 8;          // e.x < 2^25, positive
        o.y = e.y;
        csr[pos] = o;
    }
}

// ---------------- convert x -> bf16 segment of Ab ----------------

__global__ void convert_x(const float* __restrict__ x, ushort* __restrict__ Ab) {
    int gid = blockIdx.x * blockDim.x + threadIdx.x;       // one per 4 elems
    if (gid >= N_NODES * F_IN / 4) return;
    int li = gid * 4;
    int node = li >> 8;
    int c = li & 255;
    float4 v = *reinterpret_cast<const float4*>(&x[li]);
    ushort4 o;
    o.x = f2b(v.x); o.y = f2b(v.y); o.z = f2b(v.z); o.w = f2b(v.w);
    *reinterpret_cast<ushort4*>(&Ab[(size_t)node * K_TOT + c]) = o;
}

// ---------------- SpMM (bf16 in, bf16 out, fp32 accumulate) ----------------
// R5 structure kept: R3 (64-lane/edge, 8-deep) and R5 (32-lane/edge, 4-deep,
// named regs) both land at 217-221us / ~3.75 TB/s with no spill -> two
// different schedules hitting the same BW = the random-512B-gather pattern
// ceiling (~55-60% of streaming achievable over a 51MB footprint). Accepted
// as this kernel's roofline; no further schedule tuning.

__global__ void __launch_bounds__(256, 2)
spmm_bf16(const int* __restrict__ row_off, const int2* __restrict__ csr,
          const ushort* __restrict__ h, int hs,
          ushort* __restrict__ y, int ys) {
    int wave = threadIdx.x >> 6;
    int lane = threadIdx.x & 63;
    int row = blockIdx.x * 4 + wave;
    if (row >= N_NODES) return;
    int s = row_off[row];
    int e = row_off[row + 1];
    const int half = lane >> 5;
    const int fl = lane & 31;
    const size_t foff = (size_t)fl * 8;

    float acc[8];
#pragma unroll
    for (int k = 0; k < 8; k++) acc[k] = 0.f;

    int j = s;
    // peel to even alignment so int4 CSR loads are 16B-aligned
    if ((j & 1) && j < e) {
        int2 e0 = csr[j];
        float v = half ? 0.f : __int_as_float(e0.y);
        ushortx8 g = *reinterpret_cast<const ushortx8*>(&h[(size_t)e0.x * hs + foff]);
#pragma unroll
        for (int k = 0; k < 8; k++) acc[k] += v * b2f((ushort)g[k]);
        j++;
    }

#define CSR_LD(dst, idx) int4 dst = *reinterpret_cast<const int4*>(&csr[j + 2 * (idx)])
#define GATHER(gdst, ee) ushortx8 gdst = *reinterpret_cast<const ushortx8*>( \
        &h[(size_t)(half ? (ee).z : (ee).x) * hs + foff])
#define CONSUME(gg, ee) { float v_ = __int_as_float(half ? (ee).w : (ee).y); \
        _Pragma("unroll") for (int k = 0; k < 8; k++) acc[k] += v_ * b2f((ushort)(gg)[k]); }

    for (; j + 8 <= e; j += 8) {
        CSR_LD(e0, 0); CSR_LD(e1, 1); CSR_LD(e2, 2); CSR_LD(e3, 3);
        GATHER(g0, e0); GATHER(g1, e1); GATHER(g2, e2); GATHER(g3, e3);
        CONSUME(g0, e0); CONSUME(g1, e1); CONSUME(g2, e2); CONSUME(g3, e3);
    }
    for (; j + 2 <= e; j += 2) {
        CSR_LD(e0, 0);
        GATHER(g0, e0);
        CONSUME(g0, e0);
    }
    if (j < e) {
        int2 e0 = csr[j];
        float v = half ? 0.f : __int_as_float(e0.y);
        ushortx8 g = *reinterpret_cast<const ushortx8*>(&h[(size_t)e0.x * hs + foff]);
#pragma unroll
        for (int k = 0; k < 8; k++) acc[k] += v * b2f((ushort)g[k]);
    }
#undef CSR_LD
#undef GATHER
#undef CONSUME

    // cross-half combine: lane l and l^32 hold partial sums of the same features
#pragma unroll
    for (int k = 0; k < 8; k++) acc[k] += __shfl_xor(acc[k], 32);

    if (half == 0) {
        ushortx8 o;
#pragma unroll
        for (int k = 0; k < 8; k++) o[k] = f2b(acc[k]);
        *reinterpret_cast<ushortx8*>(&y[(size_t)row * ys + foff]) = o;
    }
}

// ---------------- weight / BN prep ----------------
// Wt: bf16, K-major: Wt[n][kg], n in 0..511, kg in 0..1023
// kg seg 0 = sum_j w{a,b}_x[j]; seg s=1..3 = w{a,b}_adj[s-1]

__global__ void build_weights_t(const float* __restrict__ wa_x, const float* __restrict__ wa_adj,
                                const float* __restrict__ wb_x, const float* __restrict__ wb_adj,
                                ushort* __restrict__ Wt) {
    int idx = blockIdx.x * blockDim.x + threadIdx.x;
    if (idx >= M_OUT * K_TOT) return;
    int n = idx >> 10;        // 0..511
    int kg = idx & 1023;      // 0..1023
    int seg = kg >> 8;
    int k = kg & 255;
    float w;
    if (seg == 0) {
        if (n < 256)
            w = wa_x[0 * 65536 + k * 256 + n] + wa_x[1 * 65536 + k * 256 + n] + wa_x[2 * 65536 + k * 256 + n];
        else {
            int nn = n - 256;
            w = wb_x[0 * 65536 + k * 256 + nn] + wb_x[1 * 65536 + k * 256 + nn] + wb_x[2 * 65536 + k * 256 + nn];
        }
    } else {
        int s = seg - 1;
        if (n < 256) w = wa_adj[s * 65536 + k * 256 + n];
        else         w = wb_adj[s * 65536 + k * 256 + (n - 256)];
    }
    Wt[idx] = f2b(w);
}

__global__ void build_bn(const float* __restrict__ ga, const float* __restrict__ ba,
                         const float* __restrict__ ma, const float* __restrict__ va,
                         const float* __restrict__ gb, const float* __restrict__ bb,
                         const float* __restrict__ mb, const float* __restrict__ vb,
                         float* __restrict__ scale, float* __restrict__ bias) {
    int c = blockIdx.x * blockDim.x + threadIdx.x;
    if (c >= 512) return;
    float g, b, m, v;
    if (c < 256) { g = ga[c]; b = ba[c]; m = ma[c]; v = va[c]; }
    else { int cc = c - 256; g = gb[cc]; b = bb[cc]; m = mb[cc]; v = vb[cc]; }
    float s = g / sqrtf(v + EPS_BN);
    scale[c] = s;
    bias[c] = b - m * s;
}

// ---------------- MFMA GEMM: C[N,512] = Ab[N,1024] @ Wt^T, fused relu+BN ----------------
// block = 256 threads = 4 waves (2x2), block tile 128x128, wave tile 64x64
// Ab row-major [m][k]; Wt K-major [n][k]  =>  both staged identically.
// LDS stride 40 elems (80 B): rows hit banks with period 8 -> 2-way (free).
// R6: XCD-bijective block swizzle. Grid = 3128 = 8*391 exactly. Round-robin
// dispatch puts orig-id o on XCD (o&7); swz=(o&7)*391+(o>>3) gives each XCD a
// contiguous swz range with the 4 n-blocks of each m-panel temporally adjacent
// on ONE XCD -> A-panel (256KB) fetched once into that XCD's 4MB L2 and
// reused 4x. A fabric traffic 820MB -> ~230MB.

#define LDS_STRIDE 40
#define GEMM_MBLKS 782           // ceil(100000/128)
#define GEMM_GRID (GEMM_MBLKS * 4)
#define GEMM_CPX (GEMM_GRID / 8) // 391, exact

__global__ void gemm_mfma(const ushort* __restrict__ Ab, const ushort* __restrict__ Wt,
                          float* __restrict__ C,
                          const float* __restrict__ scale, const float* __restrict__ bias) {
    __shared__ ushort As[128 * LDS_STRIDE];
    __shared__ ushort Bs[128 * LDS_STRIDE];
    const int tid = threadIdx.x;
    const int lane = tid & 63;
    const int wave = tid >> 6;
    const int wm = wave >> 1;       // wave row half (0/1)
    const int wn = wave & 1;        // wave col half (0/1)
    const int quad = lane >> 4;
    const int l16 = lane & 15;
    // XCD-bijective swizzle: o&7 = XCD; each XCD walks m-panels in order with
    // the 4 n-blocks of a panel adjacent.
    const int o = blockIdx.x;
    const int swz = (o & 7) * GEMM_CPX + (o >> 3);
    const int mBase = (swz >> 2) * 128;
    const int nBase = (swz & 3) * 128;

    floatx4 acc[4][4];
#pragma unroll
    for (int i = 0; i < 4; i++)
#pragma unroll
        for (int j = 0; j < 4; j++) acc[i][j] = (floatx4){0.f, 0.f, 0.f, 0.f};

    for (int k0 = 0; k0 < K_TOT; k0 += 32) {
        // stage A and B tiles: 128 rows x 32 cols bf16 each
#pragma unroll
        for (int p = 0; p < 2; p++) {
            int li = tid + p * 256;
            int row = li >> 2;             // 0..127
            int c8 = (li & 3) * 8;         // 0,8,16,24
            int gm = mBase + row; if (gm > N_NODES - 1) gm = N_NODES - 1;
            uint4 va = *reinterpret_cast<const uint4*>(&Ab[(size_t)gm * K_TOT + k0 + c8]);
            uint4 vb = *reinterpret_cast<const uint4*>(&Wt[(size_t)(nBase + row) * K_TOT + k0 + c8]);
            *reinterpret_cast<uint4*>(&As[row * LDS_STRIDE + c8]) = va;
            *reinterpret_cast<uint4*>(&Bs[row * LDS_STRIDE + c8]) = vb;
        }
        __syncthreads();

        short8 a_frag[4], b_frag[4];
#pragma unroll
        for (int i = 0; i < 4; i++)
            a_frag[i] = *reinterpret_cast<const short8*>(&As[(wm * 64 + i * 16 + l16) * LDS_STRIDE + quad * 8]);
#pragma unroll
        for (int j = 0; j < 4; j++)
            b_frag[j] = *reinterpret_cast<const short8*>(&Bs[(wn * 64 + j * 16 + l16) * LDS_STRIDE + quad * 8]);
#pragma unroll
        for (int i = 0; i < 4; i++)
#pragma unroll
            for (int j = 0; j < 4; j++)
                acc[i][j] = __builtin_amdgcn_mfma_f32_16x16x32_bf16(a_frag[i], b_frag[j], acc[i][j], 0, 0, 0);
        __syncthreads();
    }

    // epilogue: relu on cols < 256, then BN affine; C row-major [m][512]
    float sc[4], bs[4];
    int gncol[4];
#pragma unroll
    for (int j = 0; j < 4; j++) {
        int gn = nBase + wn * 64 + j * 16 + l16;
        gncol[j] = gn;
        sc[j] = scale[gn];
        bs[j] = bias[gn];
    }
#pragma unroll
    for (int i = 0; i < 4; i++) {
#pragma unroll
        for (int r = 0; r < 4; r++) {
            int gm = mBase + wm * 64 + i * 16 + quad * 4 + r;
            if (gm >= N_NODES) continue;
#pragma unroll
            for (int j = 0; j < 4; j++) {
                float v = acc[i][j][r];
                if (gncol[j] < 256) v = fmaxf(v, 0.f);
                v = v * sc[j] + bs[j];
                C[(size_t)gm * M_OUT + gncol[j]] = v;
            }
        }
    }
}

// ---------------- launch ----------------

static inline size_t align_up(size_t x, size_t a) { return (x + a - 1) & ~(a - 1); }

extern "C" void kernel_launch(void* const* d_in, const int* in_sizes, int n_in,
                              void* d_out, int out_size, void* d_ws, size_t ws_size,
                              hipStream_t stream) {
    const float* x      = (const float*)d_in[0];
    const int*   erow   = (const int*)d_in[1];
    const int*   ecol   = (const int*)d_in[2];
    const float* eval   = (const float*)d_in[3];
    const float* wa_x   = (const float*)d_in[4];
    const float* wa_adj = (const float*)d_in[5];
    const float* wb_x   = (const float*)d_in[6];
    const float* wb_adj = (const float*)d_in[7];
    const float* ga = (const float*)d_in[8];
    const float* ba = (const float*)d_in[9];
    const float* ma = (const float*)d_in[10];
    const float* va = (const float*)d_in[11];
    const float* gb = (const float*)d_in[12];
    const float* bb = (const float*)d_in[13];
    const float* mb = (const float*)d_in[14];
    const float* vb = (const float*)d_in[15];
    float* out = (float*)d_out;

    char* ws = (char*)d_ws;
    size_t off = 0;
    int*    row_off   = (int*)(ws + off);    off = align_up(off + (size_t)(N_NODES + 1) * 4, 1024);
    int*    cursor    = (int*)(ws + off);    off = align_up(off + (size_t)N_NODES * 4, 1024);
    int*    chunkSums = (int*)(ws + off);    off = align_up(off + (size_t)NUM_CHUNKS * 4, 1024);
    int2*   csr       = (int2*)(ws + off);   off = align_up(off + (size_t)N_EDGES * 8, 1024);
    ushort* Wt        = (ushort*)(ws + off); off = align_up(off + (size_t)M_OUT * K_TOT * 2, 1024);
    float*  scale     = (float*)(ws + off);  off = align_up(off + 512 * 4, 1024);
    float*  bias      = (float*)(ws + off);  off = align_up(off + 512 * 4, 1024);
    ushort* Ab        = (ushort*)(ws + off); off = align_up(off + (size_t)N_NODES * K_TOT * 2, 1024);
    ushort* tmp       = (ushort*)(ws + off); off = align_up(off + (size_t)N_NODES * F_IN * 2, 1024);
    // pass-1 temp edge buffer aliases the hop scratch (stream-serial: pass1/pass2
    // complete before the spmm chain touches tmp). 25.6MB <= 51.2MB.
    int2*   tmpE      = (int2*)tmp;
    (void)ws_size; (void)in_sizes; (void)n_in; (void)out_size;

    const int zeroBlocks = (N_NODES + 255) / 256;
    const int edgeBlocks = (N_EDGES + 255) / 256;
    const int p1Blocks = (N_EDGES + EPB - 1) / EPB;

    // ---- CSR build ----
    zero_i32<<<zeroBlocks, 256, 0, stream>>>(cursor, N_NODES);
    hist_kernel<<<edgeBlocks, 256, 0, stream>>>(erow, cursor, N_EDGES);
    scan_chunk_sums<<<NUM_CHUNKS, 256, 0, stream>>>(cursor, chunkSums, N_NODES);
    scan_spine<<<1, 512, 0, stream>>>(chunkSums, NUM_CHUNKS, row_off, N_NODES);
    scan_final<<<NUM_CHUNKS, 256, 0, stream>>>(cursor, chunkSums, row_off, N_NODES);
    // reuse cursor[0..NB) as per-bucket global cursors
    zero_i32<<<(NB + 255) / 256, 256, 0, stream>>>(cursor, NB);
    scatter_pass1<<<p1Blocks, 256, 0, stream>>>(erow, ecol, eval, chunkSums, cursor, tmpE);
    scatter_pass2<<<NB, 256, 0, stream>>>(tmpE, chunkSums, row_off, csr);

    // ---- weight & BN prep ----
    build_weights_t<<<(M_OUT * K_TOT) / 256, 256, 0, stream>>>(wa_x, wa_adj, wb_x, wb_adj, Wt);
    build_bn<<<2, 256, 0, stream>>>(ga, ba, ma, va, gb, bb, mb, vb, scale, bias);

    // ---- x -> bf16 (segment 0 of Ab) ----
    convert_x<<<(N_NODES * F_IN / 4 + 255) / 256, 256, 0, stream>>>(x, Ab);

    // ---- hop chain (bf16 storage, fp32 accumulate) ----
    const int spmmBlocks = (N_NODES + 3) / 4;
    spmm_bf16<<<spmmBlocks, 256, 0, stream>>>(row_off, csr,
                                              Ab + 0 * 256, K_TOT, Ab + 1 * 256, K_TOT);   // A x
    spmm_bf16<<<spmmBlocks, 256, 0, stream>>>(row_off, csr,
                                              Ab + 1 * 256, K_TOT, Ab + 2 * 256, K_TOT);   // A^2 x
    spmm_bf16<<<spmmBlocks, 256, 0, stream>>>(row_off, csr,
                                              Ab + 2 * 256, K_TOT, tmp, F_IN);             // A^3 x
    spmm_bf16<<<spmmBlocks, 256, 0, stream>>>(row_off, csr,
                                              tmp, F_IN, Ab + 3 * 256, K_TOT);             // A^4 x

    // ---- fused GEMM + relu + BN ----
    gemm_mfma<<<GEMM_GRID, 256, 0, stream>>>(Ab, Wt, out, scale, bias);
}

// Round 5
// 1469.942 us; speedup vs baseline: 1.7117x; 1.0707x over previous
//
#include <hip/hip_runtime.h>
#include <math.h>

#define N_NODES 100000
#define N_EDGES 3200000
#define F_IN 256
#define M_OUT 512            // 2*F_OUT concat
#define K_TOT 1024           // [x | Ax | A^2x | A^4x]
#define EPS_BN 1e-3f
#define NUM_CHUNKS 391       // ceil(100000/256) == number of row buckets
#define NB NUM_CHUNKS
#define EPB 16384            // edges per block in bin pass
#define CAP 12288            // slab capacity per bucket (mean 8184, sd~90 -> 45 sd margin)

typedef __attribute__((ext_vector_type(8))) short short8;
typedef __attribute__((ext_vector_type(8))) ushort ushortx8;
typedef __attribute__((ext_vector_type(4))) float floatx4;

__device__ __forceinline__ ushort f2b(float f) {
    union { float f; unsigned u; } c; c.f = f;
    unsigned u = c.u;
    unsigned r = (u + 0x7FFFu + ((u >> 16) & 1u)) >> 16;   // RNE
    return (ushort)r;
}
__device__ __forceinline__ float b2f(ushort b) {
    union { unsigned u; float f; } c; c.u = ((unsigned)b) << 16;
    return c.f;
}

// ---------------- small utility kernels ----------------

__global__ void zero_i32(int* __restrict__ p, int n) {
    int i = blockIdx.x * blockDim.x + threadIdx.x;
    if (i < n) p[i] = 0;
}

// ---------------- fused bucketed CSR build ----------------
// R7: the global per-row histogram + 2 scan kernels are redundant given the
// bucket structure. p1_bin bins edges into FIXED-CAPACITY per-bucket slabs
// (no prefix sums needed); spine2 scans the 391 bucket totals; p2_build
// LDS-histograms each bucket's ~8.2K edges by rowLocal, LDS-scans 256
// counters -> writes row_off directly, then reorders into final CSR.
// Replaces {zero,hist(3.2M global atomics),chunk_sums,spine,final,zero,p1,p2}
// (8 dispatches) with {zero(391),p1_bin,spine2,p2_build} (4 dispatches).

__global__ void p1_bin(const int* __restrict__ row, const int* __restrict__ col,
                       const float* __restrict__ val,
                       int* __restrict__ gcur, int2* __restrict__ slab) {
    __shared__ int cnt[NB];
    __shared__ int base[NB];
    const int t = threadIdx.x;
    const int bs = blockIdx.x * EPB;
    const int be = min(N_EDGES, bs + EPB);
    for (int b = t; b < NB; b += 256) cnt[b] = 0;
    __syncthreads();
    for (int i = bs + t; i < be; i += 256) {
        atomicAdd(&cnt[row[i] >> 8], 1);
    }
    __syncthreads();
    for (int b = t; b < NB; b += 256) {
        int c = cnt[b];
        base[b] = b * CAP + (c ? atomicAdd(&gcur[b], c) : 0);
        cnt[b] = 0;
    }
    __syncthreads();
    for (int i = bs + t; i < be; i += 256) {
        int r = row[i];
        int b = r >> 8;
        int pos = base[b] + atomicAdd(&cnt[b], 1);
        int2 e;
        e.x = (col[i] << 8) | (r & 255);
        e.y = __float_as_int(val[i]);
        slab[pos] = e;
    }
}

__global__ void spine2(const int* __restrict__ cnts, int* __restrict__ bucketOff,
                       int* __restrict__ row_off) {
    __shared__ int sm[512];
    int t = threadIdx.x;
    int v = (t < NB) ? cnts[t] : 0;
    sm[t] = v;
    __syncthreads();
    for (int s = 1; s < 512; s <<= 1) {
        int add = (t >= s) ? sm[t - s] : 0;
        __syncthreads();
        sm[t] += add;
        __syncthreads();
    }
    if (t < NB) bucketOff[t] = sm[t] - v;    // exclusive
    if (t == 0) row_off[N_NODES] = N_EDGES;
}

__global__ void p2_build(const int2* __restrict__ slab, const int* __restrict__ cnts,
                         const int* __restrict__ bucketOff,
                         int* __restrict__ row_off, int2* __restrict__ csr) {
    __shared__ int hist[256];
    __shared__ int sm[256];
    __shared__ int roff[256];
    __shared__ int lcur[256];
    const int b = blockIdx.x;
    const int t = threadIdx.x;
    hist[t] = 0;
    __syncthreads();
    const int cnt = cnts[b];
    const int2* seg = &slab[(size_t)b * CAP];
    for (int i = t; i < cnt; i += 256) atomicAdd(&hist[seg[i].x & 255], 1);
    __syncthreads();
    // exclusive scan of hist
    int v = hist[t];
    sm[t] = v;
    __syncthreads();
    for (int s = 1; s < 256; s <<= 1) {
        int add = (t >= s) ? sm[t - s] : 0;
        __syncthreads();
        sm[t] += add;
        __syncthreads();
    }
    const int base = bucketOff[b];
    const int start = base + sm[t] - v;
    const int gr = (b << 8) + t;
    if (gr < N_NODES) row_off[gr] = start;
    roff[t] = start;
    lcur[t] = 0;
    __syncthreads();
    for (int i = t; i < cnt; i += 256) {
        int2 e = seg[i];
        int rl = e.x & 255;
        int pos = roff[rl] + atomicAdd(&lcur[rl], 1);
        int2 o;
        o.x = e.x >> 8;          // e.x < 2^25, positive
        o.y = e.y;
        csr[pos] = o;
    }
}

// ---------------- convert x -> bf16 segment of Ab ----------------

__global__ void convert_x(const float* __restrict__ x, ushort* __restrict__ Ab) {
    int gid = blockIdx.x * blockDim.x + threadIdx.x;       // one per 4 elems
    if (gid >= N_NODES * F_IN / 4) return;
    int li = gid * 4;
    int node = li >> 8;
    int c = li & 255;
    float4 v = *reinterpret_cast<const float4*>(&x[li]);
    ushort4 o;
    o.x = f2b(v.x); o.y = f2b(v.y); o.z = f2b(v.z); o.w = f2b(v.w);
    *reinterpret_cast<ushort4*>(&Ab[(size_t)node * K_TOT + c]) = o;
}

// ---------------- SpMM (bf16 in, bf16 out, fp32 accumulate) ----------------
// R5 structure kept: R3 (64-lane/edge, 8-deep) and R5 (32-lane/edge, 4-deep,
// named regs) both land at 217-221us / ~3.75 TB/s with no spill -> two
// different schedules hitting the same BW = the random-512B-gather pattern
// ceiling. Accepted as this kernel's roofline; no further schedule tuning.

__global__ void __launch_bounds__(256, 2)
spmm_bf16(const int* __restrict__ row_off, const int2* __restrict__ csr,
          const ushort* __restrict__ h, int hs,
          ushort* __restrict__ y, int ys) {
    int wave = threadIdx.x >> 6;
    int lane = threadIdx.x & 63;
    int row = blockIdx.x * 4 + wave;
    if (row >= N_NODES) return;
    int s = row_off[row];
    int e = row_off[row + 1];
    const int half = lane >> 5;
    const int fl = lane & 31;
    const size_t foff = (size_t)fl * 8;

    float acc[8];
#pragma unroll
    for (int k = 0; k < 8; k++) acc[k] = 0.f;

    int j = s;
    // peel to even alignment so int4 CSR loads are 16B-aligned
    if ((j & 1) && j < e) {
        int2 e0 = csr[j];
        float v = half ? 0.f : __int_as_float(e0.y);
        ushortx8 g = *reinterpret_cast<const ushortx8*>(&h[(size_t)e0.x * hs + foff]);
#pragma unroll
        for (int k = 0; k < 8; k++) acc[k] += v * b2f((ushort)g[k]);
        j++;
    }

#define CSR_LD(dst, idx) int4 dst = *reinterpret_cast<const int4*>(&csr[j + 2 * (idx)])
#define GATHER(gdst, ee) ushortx8 gdst = *reinterpret_cast<const ushortx8*>( \
        &h[(size_t)(half ? (ee).z : (ee).x) * hs + foff])
#define CONSUME(gg, ee) { float v_ = __int_as_float(half ? (ee).w : (ee).y); \
        _Pragma("unroll") for (int k = 0; k < 8; k++) acc[k] += v_ * b2f((ushort)(gg)[k]); }

    for (; j + 8 <= e; j += 8) {
        CSR_LD(e0, 0); CSR_LD(e1, 1); CSR_LD(e2, 2); CSR_LD(e3, 3);
        GATHER(g0, e0); GATHER(g1, e1); GATHER(g2, e2); GATHER(g3, e3);
        CONSUME(g0, e0); CONSUME(g1, e1); CONSUME(g2, e2); CONSUME(g3, e3);
    }
    for (; j + 2 <= e; j += 2) {
        CSR_LD(e0, 0);
        GATHER(g0, e0);
        CONSUME(g0, e0);
    }
    if (j < e) {
        int2 e0 = csr[j];
        float v = half ? 0.f : __int_as_float(e0.y);
        ushortx8 g = *reinterpret_cast<const ushortx8*>(&h[(size_t)e0.x * hs + foff]);
#pragma unroll
        for (int k = 0; k < 8; k++) acc[k] += v * b2f((ushort)g[k]);
    }
#undef CSR_LD
#undef GATHER
#undef CONSUME

    // cross-half combine: lane l and l^32 hold partial sums of the same features
#pragma unroll
    for (int k = 0; k < 8; k++) acc[k] += __shfl_xor(acc[k], 32);

    if (half == 0) {
        ushortx8 o;
#pragma unroll
        for (int k = 0; k < 8; k++) o[k] = f2b(acc[k]);
        *reinterpret_cast<ushortx8*>(&y[(size_t)row * ys + foff]) = o;
    }
}

// ---------------- weight / BN prep ----------------
// Wt: bf16, K-major: Wt[n][kg], n in 0..511, kg in 0..1023
// kg seg 0 = sum_j w{a,b}_x[j]; seg s=1..3 = w{a,b}_adj[s-1]

__global__ void build_weights_t(const float* __restrict__ wa_x, const float* __restrict__ wa_adj,
                                const float* __restrict__ wb_x, const float* __restrict__ wb_adj,
                                ushort* __restrict__ Wt) {
    int idx = blockIdx.x * blockDim.x + threadIdx.x;
    if (idx >= M_OUT * K_TOT) return;
    int n = idx >> 10;        // 0..511
    int kg = idx & 1023;      // 0..1023
    int seg = kg >> 8;
    int k = kg & 255;
    float w;
    if (seg == 0) {
        if (n < 256)
            w = wa_x[0 * 65536 + k * 256 + n] + wa_x[1 * 65536 + k * 256 + n] + wa_x[2 * 65536 + k * 256 + n];
        else {
            int nn = n - 256;
            w = wb_x[0 * 65536 + k * 256 + nn] + wb_x[1 * 65536 + k * 256 + nn] + wb_x[2 * 65536 + k * 256 + nn];
        }
    } else {
        int s = seg - 1;
        if (n < 256) w = wa_adj[s * 65536 + k * 256 + n];
        else         w = wb_adj[s * 65536 + k * 256 + (n - 256)];
    }
    Wt[idx] = f2b(w);
}

__global__ void build_bn(const float* __restrict__ ga, const float* __restrict__ ba,
                         const float* __restrict__ ma, const float* __restrict__ va,
                         const float* __restrict__ gb, const float* __restrict__ bb,
                         const float* __restrict__ mb, const float* __restrict__ vb,
                         float* __restrict__ scale, float* __restrict__ bias) {
    int c = blockIdx.x * blockDim.x + threadIdx.x;
    if (c >= 512) return;
    float g, b, m, v;
    if (c < 256) { g = ga[c]; b = ba[c]; m = ma[c]; v = va[c]; }
    else { int cc = c - 256; g = gb[cc]; b = bb[cc]; m = mb[cc]; v = vb[cc]; }
    float s = g / sqrtf(v + EPS_BN);
    scale[c] = s;
    bias[c] = b - m * s;
}

// ---------------- MFMA GEMM: C[N,512] = Ab[N,1024] @ Wt^T, fused relu+BN ----------------
// block = 256 threads = 4 waves (2x2), block tile 128x128, wave tile 64x64
// Ab row-major [m][k]; Wt K-major [n][k]  =>  both staged identically.
// LDS stride 40 elems (80 B): rows hit banks with period 8 -> 2-way (free).
// XCD-bijective swizzle kept from R6 (neutral-to-slightly-positive).

#define LDS_STRIDE 40
#define GEMM_MBLKS 782           // ceil(100000/128)
#define GEMM_GRID (GEMM_MBLKS * 4)
#define GEMM_CPX (GEMM_GRID / 8) // 391, exact

__global__ void gemm_mfma(const ushort* __restrict__ Ab, const ushort* __restrict__ Wt,
                          float* __restrict__ C,
                          const float* __restrict__ scale, const float* __restrict__ bias) {
    __shared__ ushort As[128 * LDS_STRIDE];
    __shared__ ushort Bs[128 * LDS_STRIDE];
    const int tid = threadIdx.x;
    const int lane = tid & 63;
    const int wave = tid >> 6;
    const int wm = wave >> 1;       // wave row half (0/1)
    const int wn = wave & 1;        // wave col half (0/1)
    const int quad = lane >> 4;
    const int l16 = lane & 15;
    const int o = blockIdx.x;
    const int swz = (o & 7) * GEMM_CPX + (o >> 3);
    const int mBase = (swz >> 2) * 128;
    const int nBase = (swz & 3) * 128;

    floatx4 acc[4][4];
#pragma unroll
    for (int i = 0; i < 4; i++)
#pragma unroll
        for (int j = 0; j < 4; j++) acc[i][j] = (floatx4){0.f, 0.f, 0.f, 0.f};

    for (int k0 = 0; k0 < K_TOT; k0 += 32) {
        // stage A and B tiles: 128 rows x 32 cols bf16 each
#pragma unroll
        for (int p = 0; p < 2; p++) {
            int li = tid + p * 256;
            int row = li >> 2;             // 0..127
            int c8 = (li & 3) * 8;         // 0,8,16,24
            int gm = mBase + row; if (gm > N_NODES - 1) gm = N_NODES - 1;
            uint4 va = *reinterpret_cast<const uint4*>(&Ab[(size_t)gm * K_TOT + k0 + c8]);
            uint4 vb = *reinterpret_cast<const uint4*>(&Wt[(size_t)(nBase + row) * K_TOT + k0 + c8]);
            *reinterpret_cast<uint4*>(&As[row * LDS_STRIDE + c8]) = va;
            *reinterpret_cast<uint4*>(&Bs[row * LDS_STRIDE + c8]) = vb;
        }
        __syncthreads();

        short8 a_frag[4], b_frag[4];
#pragma unroll
        for (int i = 0; i < 4; i++)
            a_frag[i] = *reinterpret_cast<const short8*>(&As[(wm * 64 + i * 16 + l16) * LDS_STRIDE + quad * 8]);
#pragma unroll
        for (int j = 0; j < 4; j++)
            b_frag[j] = *reinterpret_cast<const short8*>(&Bs[(wn * 64 + j * 16 + l16) * LDS_STRIDE + quad * 8]);
#pragma unroll
        for (int i = 0; i < 4; i++)
#pragma unroll
            for (int j = 0; j < 4; j++)
                acc[i][j] = __builtin_amdgcn_mfma_f32_16x16x32_bf16(a_frag[i], b_frag[j], acc[i][j], 0, 0, 0);
        __syncthreads();
    }

    // epilogue: relu on cols < 256, then BN affine; C row-major [m][512]
    float sc[4], bs[4];
    int gncol[4];
#pragma unroll
    for (int j = 0; j < 4; j++) {
        int gn = nBase + wn * 64 + j * 16 + l16;
        gncol[j] = gn;
        sc[j] = scale[gn];
        bs[j] = bias[gn];
    }
#pragma unroll
    for (int i = 0; i < 4; i++) {
#pragma unroll
        for (int r = 0; r < 4; r++) {
            int gm = mBase + wm * 64 + i * 16 + quad * 4 + r;
            if (gm >= N_NODES) continue;
#pragma unroll
            for (int j = 0; j < 4; j++) {
                float v = acc[i][j][r];
                if (gncol[j] < 256) v = fmaxf(v, 0.f);
                v = v * sc[j] + bs[j];
                C[(size_t)gm * M_OUT + gncol[j]] = v;
            }
        }
    }
}

// ---------------- launch ----------------

static inline size_t align_up(size_t x, size_t a) { return (x + a - 1) & ~(a - 1); }

extern "C" void kernel_launch(void* const* d_in, const int* in_sizes, int n_in,
                              void* d_out, int out_size, void* d_ws, size_t ws_size,
                              hipStream_t stream) {
    const float* x      = (const float*)d_in[0];
    const int*   erow   = (const int*)d_in[1];
    const int*   ecol   = (const int*)d_in[2];
    const float* eval   = (const float*)d_in[3];
    const float* wa_x   = (const float*)d_in[4];
    const float* wa_adj = (const float*)d_in[5];
    const float* wb_x   = (const float*)d_in[6];
    const float* wb_adj = (const float*)d_in[7];
    const float* ga = (const float*)d_in[8];
    const float* ba = (const float*)d_in[9];
    const float* ma = (const float*)d_in[10];
    const float* va = (const float*)d_in[11];
    const float* gb = (const float*)d_in[12];
    const float* bb = (const float*)d_in[13];
    const float* mb = (const float*)d_in[14];
    const float* vb = (const float*)d_in[15];
    float* out = (float*)d_out;

    char* ws = (char*)d_ws;
    size_t off = 0;
    int*    row_off   = (int*)(ws + off);    off = align_up(off + (size_t)(N_NODES + 1) * 4, 1024);
    int*    gcur      = (int*)(ws + off);    off = align_up(off + (size_t)NB * 4, 1024);
    int*    bucketOff = (int*)(ws + off);    off = align_up(off + (size_t)NB * 4, 1024);
    int2*   csr       = (int2*)(ws + off);   off = align_up(off + (size_t)N_EDGES * 8, 1024);
    ushort* Wt        = (ushort*)(ws + off); off = align_up(off + (size_t)M_OUT * K_TOT * 2, 1024);
    float*  scale     = (float*)(ws + off);  off = align_up(off + 512 * 4, 1024);
    float*  bias      = (float*)(ws + off);  off = align_up(off + 512 * 4, 1024);
    ushort* Ab        = (ushort*)(ws + off); off = align_up(off + (size_t)N_NODES * K_TOT * 2, 1024);
    ushort* tmp       = (ushort*)(ws + off); off = align_up(off + (size_t)N_NODES * F_IN * 2, 1024);
    // slab aliases the hop scratch (stream-serial: CSR build completes before
    // the spmm chain touches tmp). 391*12288*8B = 38.4MB <= 51.2MB.
    int2*   slab      = (int2*)tmp;
    (void)ws_size; (void)in_sizes; (void)n_in; (void)out_size;

    const int p1Blocks = (N_EDGES + EPB - 1) / EPB;

    // ---- fused CSR build (4 dispatches) ----
    zero_i32<<<2, 256, 0, stream>>>(gcur, NB);
    p1_bin<<<p1Blocks, 256, 0, stream>>>(erow, ecol, eval, gcur, slab);
    spine2<<<1, 512, 0, stream>>>(gcur, bucketOff, row_off);
    p2_build<<<NB, 256, 0, stream>>>(slab, gcur, bucketOff, row_off, csr);

    // ---- weight & BN prep ----
    build_weights_t<<<(M_OUT * K_TOT) / 256, 256, 0, stream>>>(wa_x, wa_adj, wb_x, wb_adj, Wt);
    build_bn<<<2, 256, 0, stream>>>(ga, ba, ma, va, gb, bb, mb, vb, scale, bias);

    // ---- x -> bf16 (segment 0 of Ab) ----
    convert_x<<<(N_NODES * F_IN / 4 + 255) / 256, 256, 0, stream>>>(x, Ab);

    // ---- hop chain (bf16 storage, fp32 accumulate) ----
    const int spmmBlocks = (N_NODES + 3) / 4;
    spmm_bf16<<<spmmBlocks, 256, 0, stream>>>(row_off, csr,
                                              Ab + 0 * 256, K_TOT, Ab + 1 * 256, K_TOT);   // A x
    spmm_bf16<<<spmmBlocks, 256, 0, stream>>>(row_off, csr,
                                              Ab + 1 * 256, K_TOT, Ab + 2 * 256, K_TOT);   // A^2 x
    spmm_bf16<<<spmmBlocks, 256, 0, stream>>>(row_off, csr,
                                              Ab + 2 * 256, K_TOT, tmp, F_IN);             // A^3 x
    spmm_bf16<<<spmmBlocks, 256, 0, stream>>>(row_off, csr,
                                              tmp, F_IN, Ab + 3 * 256, K_TOT);             // A^4 x

    // ---- fused GEMM + relu + BN ----
    gemm_mfma<<<GEMM_GRID, 256, 0, stream>>>(Ab, Wt, out, scale, bias);
}

// Round 6
// 1446.691 us; speedup vs baseline: 1.7392x; 1.0161x over previous
//
#include <hip/hip_runtime.h>
#include <math.h>

#define N_NODES 100000
#define N_EDGES 3200000
#define F_IN 256
#define M_OUT 512            // 2*F_OUT concat
#define K_TOT 1024           // [x | Ax | A^2x | A^4x]
#define EPS_BN 1e-3f
#define NUM_CHUNKS 391       // ceil(100000/256) == number of row buckets
#define NB NUM_CHUNKS
#define EPB 16384            // edges per block in bin pass
#define CAP 12288            // slab capacity per bucket (mean 8184, huge margin)

typedef __attribute__((ext_vector_type(8))) short short8;
typedef __attribute__((ext_vector_type(8))) ushort ushortx8;
typedef __attribute__((ext_vector_type(4))) float floatx4;

__device__ __forceinline__ ushort f2b(float f) {
    union { float f; unsigned u; } c; c.f = f;
    unsigned u = c.u;
    unsigned r = (u + 0x7FFFu + ((u >> 16) & 1u)) >> 16;   // RNE
    return (ushort)r;
}
__device__ __forceinline__ float b2f(ushort b) {
    union { unsigned u; float f; } c; c.u = ((unsigned)b) << 16;
    return c.f;
}

// direct global->LDS DMA, 16B per lane. dest = wave-uniform base + lane*16.
__device__ __forceinline__ void gload16(const ushort* g, ushort* l) {
    __builtin_amdgcn_global_load_lds(
        (const __attribute__((address_space(1))) unsigned int*)(const void*)g,
        (__attribute__((address_space(3))) unsigned int*)(void*)l,
        16, 0, 0);
}

// ---------------- small utility kernels ----------------

__global__ void zero_i32(int* __restrict__ p, int n) {
    int i = blockIdx.x * blockDim.x + threadIdx.x;
    if (i < n) p[i] = 0;
}

// ---------------- fused bucketed CSR build (R7, verified) ----------------

__global__ void p1_bin(const int* __restrict__ row, const int* __restrict__ col,
                       const float* __restrict__ val,
                       int* __restrict__ gcur, int2* __restrict__ slab) {
    __shared__ int cnt[NB];
    __shared__ int base[NB];
    const int t = threadIdx.x;
    const int bs = blockIdx.x * EPB;
    const int be = min(N_EDGES, bs + EPB);
    for (int b = t; b < NB; b += 256) cnt[b] = 0;
    __syncthreads();
    for (int i = bs + t; i < be; i += 256) {
        atomicAdd(&cnt[row[i] >> 8], 1);
    }
    __syncthreads();
    for (int b = t; b < NB; b += 256) {
        int c = cnt[b];
        base[b] = b * CAP + (c ? atomicAdd(&gcur[b], c) : 0);
        cnt[b] = 0;
    }
    __syncthreads();
    for (int i = bs + t; i < be; i += 256) {
        int r = row[i];
        int b = r >> 8;
        int pos = base[b] + atomicAdd(&cnt[b], 1);
        int2 e;
        e.x = (col[i] << 8) | (r & 255);
        e.y = __float_as_int(val[i]);
        slab[pos] = e;
    }
}

__global__ void spine2(const int* __restrict__ cnts, int* __restrict__ bucketOff,
                       int* __restrict__ row_off) {
    __shared__ int sm[512];
    int t = threadIdx.x;
    int v = (t < NB) ? cnts[t] : 0;
    sm[t] = v;
    __syncthreads();
    for (int s = 1; s < 512; s <<= 1) {
        int add = (t >= s) ? sm[t - s] : 0;
        __syncthreads();
        sm[t] += add;
        __syncthreads();
    }
    if (t < NB) bucketOff[t] = sm[t] - v;    // exclusive
    if (t == 0) row_off[N_NODES] = N_EDGES;
}

__global__ void p2_build(const int2* __restrict__ slab, const int* __restrict__ cnts,
                         const int* __restrict__ bucketOff,
                         int* __restrict__ row_off, int2* __restrict__ csr) {
    __shared__ int hist[256];
    __shared__ int sm[256];
    __shared__ int roff[256];
    __shared__ int lcur[256];
    const int b = blockIdx.x;
    const int t = threadIdx.x;
    hist[t] = 0;
    __syncthreads();
    const int cnt = cnts[b];
    const int2* seg = &slab[(size_t)b * CAP];
    for (int i = t; i < cnt; i += 256) atomicAdd(&hist[seg[i].x & 255], 1);
    __syncthreads();
    // exclusive scan of hist
    int v = hist[t];
    sm[t] = v;
    __syncthreads();
    for (int s = 1; s < 256; s <<= 1) {
        int add = (t >= s) ? sm[t - s] : 0;
        __syncthreads();
        sm[t] += add;
        __syncthreads();
    }
    const int base = bucketOff[b];
    const int start = base + sm[t] - v;
    const int gr = (b << 8) + t;
    if (gr < N_NODES) row_off[gr] = start;
    roff[t] = start;
    lcur[t] = 0;
    __syncthreads();
    for (int i = t; i < cnt; i += 256) {
        int2 e = seg[i];
        int rl = e.x & 255;
        int pos = roff[rl] + atomicAdd(&lcur[rl], 1);
        int2 o;
        o.x = e.x >> 8;          // e.x < 2^25, positive
        o.y = e.y;
        csr[pos] = o;
    }
}

// ---------------- convert x -> bf16 segment of Ab ----------------

__global__ void convert_x(const float* __restrict__ x, ushort* __restrict__ Ab) {
    int gid = blockIdx.x * blockDim.x + threadIdx.x;       // one per 4 elems
    if (gid >= N_NODES * F_IN / 4) return;
    int li = gid * 4;
    int node = li >> 8;
    int c = li & 255;
    float4 v = *reinterpret_cast<const float4*>(&x[li]);
    ushort4 o;
    o.x = f2b(v.x); o.y = f2b(v.y); o.z = f2b(v.z); o.w = f2b(v.w);
    *reinterpret_cast<ushort4*>(&Ab[(size_t)node * K_TOT + c]) = o;
}

// ---------------- SpMM (bf16 in, bf16 out, fp32 accumulate) ----------------
// At pattern roofline (R3/R5 cross-check: two different schedules both hit
// ~220us / ~3.77 TB/s effective on random 512B gathers). Untouched.

__global__ void __launch_bounds__(256, 2)
spmm_bf16(const int* __restrict__ row_off, const int2* __restrict__ csr,
          const ushort* __restrict__ h, int hs,
          ushort* __restrict__ y, int ys) {
    int wave = threadIdx.x >> 6;
    int lane = threadIdx.x & 63;
    int row = blockIdx.x * 4 + wave;
    if (row >= N_NODES) return;
    int s = row_off[row];
    int e = row_off[row + 1];
    const int half = lane >> 5;
    const int fl = lane & 31;
    const size_t foff = (size_t)fl * 8;

    float acc[8];
#pragma unroll
    for (int k = 0; k < 8; k++) acc[k] = 0.f;

    int j = s;
    // peel to even alignment so int4 CSR loads are 16B-aligned
    if ((j & 1) && j < e) {
        int2 e0 = csr[j];
        float v = half ? 0.f : __int_as_float(e0.y);
        ushortx8 g = *reinterpret_cast<const ushortx8*>(&h[(size_t)e0.x * hs + foff]);
#pragma unroll
        for (int k = 0; k < 8; k++) acc[k] += v * b2f((ushort)g[k]);
        j++;
    }

#define CSR_LD(dst, idx) int4 dst = *reinterpret_cast<const int4*>(&csr[j + 2 * (idx)])
#define GATHER(gdst, ee) ushortx8 gdst = *reinterpret_cast<const ushortx8*>( \
        &h[(size_t)(half ? (ee).z : (ee).x) * hs + foff])
#define CONSUME(gg, ee) { float v_ = __int_as_float(half ? (ee).w : (ee).y); \
        _Pragma("unroll") for (int k = 0; k < 8; k++) acc[k] += v_ * b2f((ushort)(gg)[k]); }

    for (; j + 8 <= e; j += 8) {
        CSR_LD(e0, 0); CSR_LD(e1, 1); CSR_LD(e2, 2); CSR_LD(e3, 3);
        GATHER(g0, e0); GATHER(g1, e1); GATHER(g2, e2); GATHER(g3, e3);
        CONSUME(g0, e0); CONSUME(g1, e1); CONSUME(g2, e2); CONSUME(g3, e3);
    }
    for (; j + 2 <= e; j += 2) {
        CSR_LD(e0, 0);
        GATHER(g0, e0);
        CONSUME(g0, e0);
    }
    if (j < e) {
        int2 e0 = csr[j];
        float v = half ? 0.f : __int_as_float(e0.y);
        ushortx8 g = *reinterpret_cast<const ushortx8*>(&h[(size_t)e0.x * hs + foff]);
#pragma unroll
        for (int k = 0; k < 8; k++) acc[k] += v * b2f((ushort)g[k]);
    }
#undef CSR_LD
#undef GATHER
#undef CONSUME

    // cross-half combine: lane l and l^32 hold partial sums of the same features
#pragma unroll
    for (int k = 0; k < 8; k++) acc[k] += __shfl_xor(acc[k], 32);

    if (half == 0) {
        ushortx8 o;
#pragma unroll
        for (int k = 0; k < 8; k++) o[k] = f2b(acc[k]);
        *reinterpret_cast<ushortx8*>(&y[(size_t)row * ys + foff]) = o;
    }
}

// ---------------- weight / BN prep ----------------

__global__ void build_weights_t(const float* __restrict__ wa_x, const float* __restrict__ wa_adj,
                                const float* __restrict__ wb_x, const float* __restrict__ wb_adj,
                                ushort* __restrict__ Wt) {
    int idx = blockIdx.x * blockDim.x + threadIdx.x;
    if (idx >= M_OUT * K_TOT) return;
    int n = idx >> 10;        // 0..511
    int kg = idx & 1023;      // 0..1023
    int seg = kg >> 8;
    int k = kg & 255;
    float w;
    if (seg == 0) {
        if (n < 256)
            w = wa_x[0 * 65536 + k * 256 + n] + wa_x[1 * 65536 + k * 256 + n] + wa_x[2 * 65536 + k * 256 + n];
        else {
            int nn = n - 256;
            w = wb_x[0 * 65536 + k * 256 + nn] + wb_x[1 * 65536 + k * 256 + nn] + wb_x[2 * 65536 + k * 256 + nn];
        }
    } else {
        int s = seg - 1;
        if (n < 256) w = wa_adj[s * 65536 + k * 256 + n];
        else         w = wb_adj[s * 65536 + k * 256 + (n - 256)];
    }
    Wt[idx] = f2b(w);
}

__global__ void build_bn(const float* __restrict__ ga, const float* __restrict__ ba,
                         const float* __restrict__ ma, const float* __restrict__ va,
                         const float* __restrict__ gb, const float* __restrict__ bb,
                         const float* __restrict__ mb, const float* __restrict__ vb,
                         float* __restrict__ scale, float* __restrict__ bias) {
    int c = blockIdx.x * blockDim.x + threadIdx.x;
    if (c >= 512) return;
    float g, b, m, v;
    if (c < 256) { g = ga[c]; b = ba[c]; m = ma[c]; v = va[c]; }
    else { int cc = c - 256; g = gb[cc]; b = bb[cc]; m = mb[cc]; v = vb[cc]; }
    float s = g / sqrtf(v + EPS_BN);
    scale[c] = s;
    bias[c] = b - m * s;
}

// ---------------- MFMA GEMM: C[N,512] = Ab[N,1024] @ Wt^T, fused relu+BN ----------------
// R8: staging via __builtin_amdgcn_global_load_lds width-16 (m151: reg-staging
// 646 TF vs gload_lds 874 TF on this exact 128x128/BK=32/2-barrier structure).
// gload_lds writes LINEAR (wave base + lane*16), so the padded stride-40 LDS is
// replaced by linear [128][32] + XOR swizzle realized through the PER-LANE
// GLOBAL SOURCE address (rule #21: linear dest + inverse-swz source + swz read):
//   physical 16B-slot of logical (row R, quarter q) = R*4 + (q ^ ((R>>1)&3))
//   -> staging lane l sources col-quarter (l&3) ^ ((l>>3)&3) of its row
//   -> ds_read addr = R*64 + ((quad ^ ((l16>>1)&3))*16)
// Bank check (lanes 0-15, fixed quad): 16B-granule group = (l16&1)*4 +
// (quad ^ ((l16>>1)&3)) -> all 8 groups x 2 lanes = 2-way = free.
// Sync structure (2 barriers/K-step) unchanged from the verified R1-R7 gemm.

#define GEMM_MBLKS 782           // ceil(100000/128)
#define GEMM_GRID (GEMM_MBLKS * 4)
#define GEMM_CPX (GEMM_GRID / 8) // 391, exact

__global__ void gemm_mfma(const ushort* __restrict__ Ab, const ushort* __restrict__ Wt,
                          float* __restrict__ C,
                          const float* __restrict__ scale, const float* __restrict__ bias) {
    __shared__ __align__(16) ushort As[128 * 32];
    __shared__ __align__(16) ushort Bs[128 * 32];
    const int tid = threadIdx.x;
    const int lane = tid & 63;
    const int wave = tid >> 6;
    const int wm = wave >> 1;       // wave row half (0/1)
    const int wn = wave & 1;        // wave col half (0/1)
    const int quad = lane >> 4;
    const int l16 = lane & 15;
    const int o = blockIdx.x;
    const int swz = (o & 7) * GEMM_CPX + (o >> 3);
    const int mBase = (swz >> 2) * 128;
    const int nBase = (swz & 3) * 128;

    // ---- staging addresses (constant across K-loop except +k0) ----
    // lane l covers row (l>>2) of its wave's 16-row stripe, sourcing the
    // swizzled quarter qsrc so data lands at the swizzled physical slot.
    const int qsrc = (lane & 3) ^ ((lane >> 3) & 3);
    const int rloc = wave * 16 + (lane >> 2);
    int gmA0 = mBase + rloc;       if (gmA0 > N_NODES - 1) gmA0 = N_NODES - 1;
    int gmA1 = mBase + rloc + 64;  if (gmA1 > N_NODES - 1) gmA1 = N_NODES - 1;
    const ushort* srcA0 = &Ab[(size_t)gmA0 * K_TOT + qsrc * 8];
    const ushort* srcA1 = &Ab[(size_t)gmA1 * K_TOT + qsrc * 8];
    const ushort* srcB0 = &Wt[(size_t)(nBase + rloc) * K_TOT + qsrc * 8];
    const ushort* srcB1 = &Wt[(size_t)(nBase + rloc + 64) * K_TOT + qsrc * 8];
    ushort* dstA0 = &As[(wave * 16) * 32];          // + lane*16B by HW
    ushort* dstA1 = &As[(64 + wave * 16) * 32];
    ushort* dstB0 = &Bs[(wave * 16) * 32];
    ushort* dstB1 = &Bs[(64 + wave * 16) * 32];

    // ds_read swizzled column offsets (ushort units)
    const int rsw = (l16 >> 1) & 3;

    floatx4 acc[4][4];
#pragma unroll
    for (int i = 0; i < 4; i++)
#pragma unroll
        for (int j = 0; j < 4; j++) acc[i][j] = (floatx4){0.f, 0.f, 0.f, 0.f};

    for (int k0 = 0; k0 < K_TOT; k0 += 32) {
        gload16(srcA0 + k0, dstA0);
        gload16(srcA1 + k0, dstA1);
        gload16(srcB0 + k0, dstB0);
        gload16(srcB1 + k0, dstB1);
        __syncthreads();   // drains vmcnt (compiler semantics) -> LDS ready

        short8 a_frag[4], b_frag[4];
#pragma unroll
        for (int i = 0; i < 4; i++)
            a_frag[i] = *reinterpret_cast<const short8*>(
                &As[(wm * 64 + i * 16 + l16) * 32 + ((quad ^ rsw) * 8)]);
#pragma unroll
        for (int j = 0; j < 4; j++)
            b_frag[j] = *reinterpret_cast<const short8*>(
                &Bs[(wn * 64 + j * 16 + l16) * 32 + ((quad ^ rsw) * 8)]);
#pragma unroll
        for (int i = 0; i < 4; i++)
#pragma unroll
            for (int j = 0; j < 4; j++)
                acc[i][j] = __builtin_amdgcn_mfma_f32_16x16x32_bf16(a_frag[i], b_frag[j], acc[i][j], 0, 0, 0);
        __syncthreads();
    }

    // epilogue: relu on cols < 256, then BN affine; C row-major [m][512]
    float sc[4], bs[4];
    int gncol[4];
#pragma unroll
    for (int j = 0; j < 4; j++) {
        int gn = nBase + wn * 64 + j * 16 + l16;
        gncol[j] = gn;
        sc[j] = scale[gn];
        bs[j] = bias[gn];
    }
#pragma unroll
    for (int i = 0; i < 4; i++) {
#pragma unroll
        for (int r = 0; r < 4; r++) {
            int gm = mBase + wm * 64 + i * 16 + quad * 4 + r;
            if (gm >= N_NODES) continue;
#pragma unroll
            for (int j = 0; j < 4; j++) {
                float v = acc[i][j][r];
                if (gncol[j] < 256) v = fmaxf(v, 0.f);
                v = v * sc[j] + bs[j];
                C[(size_t)gm * M_OUT + gncol[j]] = v;
            }
        }
    }
}

// ---------------- launch ----------------

static inline size_t align_up(size_t x, size_t a) { return (x + a - 1) & ~(a - 1); }

extern "C" void kernel_launch(void* const* d_in, const int* in_sizes, int n_in,
                              void* d_out, int out_size, void* d_ws, size_t ws_size,
                              hipStream_t stream) {
    const float* x      = (const float*)d_in[0];
    const int*   erow   = (const int*)d_in[1];
    const int*   ecol   = (const int*)d_in[2];
    const float* eval   = (const float*)d_in[3];
    const float* wa_x   = (const float*)d_in[4];
    const float* wa_adj = (const float*)d_in[5];
    const float* wb_x   = (const float*)d_in[6];
    const float* wb_adj = (const float*)d_in[7];
    const float* ga = (const float*)d_in[8];
    const float* ba = (const float*)d_in[9];
    const float* ma = (const float*)d_in[10];
    const float* va = (const float*)d_in[11];
    const float* gb = (const float*)d_in[12];
    const float* bb = (const float*)d_in[13];
    const float* mb = (const float*)d_in[14];
    const float* vb = (const float*)d_in[15];
    float* out = (float*)d_out;

    char* ws = (char*)d_ws;
    size_t off = 0;
    int*    row_off   = (int*)(ws + off);    off = align_up(off + (size_t)(N_NODES + 1) * 4, 1024);
    int*    gcur      = (int*)(ws + off);    off = align_up(off + (size_t)NB * 4, 1024);
    int*    bucketOff = (int*)(ws + off);    off = align_up(off + (size_t)NB * 4, 1024);
    int2*   csr       = (int2*)(ws + off);   off = align_up(off + (size_t)N_EDGES * 8, 1024);
    ushort* Wt        = (ushort*)(ws + off); off = align_up(off + (size_t)M_OUT * K_TOT * 2, 1024);
    float*  scale     = (float*)(ws + off);  off = align_up(off + 512 * 4, 1024);
    float*  bias      = (float*)(ws + off);  off = align_up(off + 512 * 4, 1024);
    ushort* Ab        = (ushort*)(ws + off); off = align_up(off + (size_t)N_NODES * K_TOT * 2, 1024);
    ushort* tmp       = (ushort*)(ws + off); off = align_up(off + (size_t)N_NODES * F_IN * 2, 1024);
    // slab aliases the hop scratch (stream-serial: CSR build completes before
    // the spmm chain touches tmp). 391*12288*8B = 38.4MB <= 51.2MB.
    int2*   slab      = (int2*)tmp;
    (void)ws_size; (void)in_sizes; (void)n_in; (void)out_size;

    const int p1Blocks = (N_EDGES + EPB - 1) / EPB;

    // ---- fused CSR build (4 dispatches) ----
    zero_i32<<<2, 256, 0, stream>>>(gcur, NB);
    p1_bin<<<p1Blocks, 256, 0, stream>>>(erow, ecol, eval, gcur, slab);
    spine2<<<1, 512, 0, stream>>>(gcur, bucketOff, row_off);
    p2_build<<<NB, 256, 0, stream>>>(slab, gcur, bucketOff, row_off, csr);

    // ---- weight & BN prep ----
    build_weights_t<<<(M_OUT * K_TOT) / 256, 256, 0, stream>>>(wa_x, wa_adj, wb_x, wb_adj, Wt);
    build_bn<<<2, 256, 0, stream>>>(ga, ba, ma, va, gb, bb, mb, vb, scale, bias);

    // ---- x -> bf16 (segment 0 of Ab) ----
    convert_x<<<(N_NODES * F_IN / 4 + 255) / 256, 256, 0, stream>>>(x, Ab);

    // ---- hop chain (bf16 storage, fp32 accumulate) ----
    const int spmmBlocks = (N_NODES + 3) / 4;
    spmm_bf16<<<spmmBlocks, 256, 0, stream>>>(row_off, csr,
                                              Ab + 0 * 256, K_TOT, Ab + 1 * 256, K_TOT);   // A x
    spmm_bf16<<<spmmBlocks, 256, 0, stream>>>(row_off, csr,
                                              Ab + 1 * 256, K_TOT, Ab + 2 * 256, K_TOT);   // A^2 x
    spmm_bf16<<<spmmBlocks, 256, 0, stream>>>(row_off, csr,
                                              Ab + 2 * 256, K_TOT, tmp, F_IN);             // A^3 x
    spmm_bf16<<<spmmBlocks, 256, 0, stream>>>(row_off, csr,
                                              tmp, F_IN, Ab + 3 * 256, K_TOT);             // A^4 x

    // ---- fused GEMM + relu + BN ----
    gemm_mfma<<<GEMM_GRID, 256, 0, stream>>>(Ab, Wt, out, scale, bias);
}